// Round 4
// baseline (1687.787 us; speedup 1.0000x reference)
//
#include <hip/hip_runtime.h>
#include <cstddef>
#include <cstdint>

#define NUC 40000
#define NIC 60000
#define NC  100000

typedef short  short8 __attribute__((ext_vector_type(8)));
typedef float  f32x4  __attribute__((ext_vector_type(4)));

__device__ __forceinline__ float lrelu(float x) { return x >= 0.f ? x : 0.01f * x; }

__device__ __forceinline__ unsigned short f2bf(float f) {
    unsigned int u = __builtin_bit_cast(unsigned int, f);
    u += 0x7fffu + ((u >> 16) & 1u);           // RNE
    return (unsigned short)(u >> 16);
}
__device__ __forceinline__ float bf2f(unsigned int us) {
    return __builtin_bit_cast(float, us << 16);
}

enum { EPI_NONE = 0, EPI_BIAS = 1, EPI_LIN = 2, EPI_G = 3 };

// ================= main MFMA GEMM, 2-phase reg-prefetch pipeline =================
// C[M,BN] = epi( A[M,K] @ Wt^T ), Wt bf16 [BN][K]. WN=4: 64x256 block; WN=1: 256x64.
template<int EPI, bool A_BF16, bool OUT_BF16, int WN>
__global__ __launch_bounds__(256)
void gemm_mfma(const void* __restrict__ Av, const unsigned short* __restrict__ Wt,
               const float* __restrict__ bias, const float* __restrict__ extra,
               void* __restrict__ Cv, int M, int K)
{
    constexpr int BM = (WN == 4) ? 64 : 256;
    constexpr int BN = WN * 64;
    constexpr int CA_F = BM * 32 / (256 * 4);   // float4 chunks/thread (f32 A)
    constexpr int CA_B = BM * 32 / (256 * 8);   // uint4 chunks/thread (bf16 A)
    constexpr int CB   = BN * 32 / (256 * 8);   // uint4 chunks/thread (B)

    __shared__ __align__(16) unsigned short Al[BM][32];
    __shared__ __align__(16) unsigned short Bl[BN][32];

    const int t = threadIdx.x;
    const int wave = t >> 6, lane = t & 63;
    const int wm = (WN == 4) ? 0 : wave;
    const int wn = (WN == 4) ? wave : 0;
    const int row0 = blockIdx.x * BM;
    const int fr = lane & 15, fk = lane >> 4;

    const float*          Af = (const float*)Av;
    const unsigned short* Ab = (const unsigned short*)Av;

    float4 paf[2][CA_F ? CA_F : 1];
    uint4  pab[2][CA_B ? CA_B : 1];
    uint4  pb[2][CB];
    f32x4  acc[4][4] = {};

#define LOAD_TILE(S, K0)                                                        \
    {   const int k0_ = (K0);                                                   \
        if constexpr (A_BF16) {                                                 \
            _Pragma("unroll")                                                   \
            for (int q = 0; q < CA_B; ++q) {                                    \
                int idx = q * 256 + t; int r = idx >> 2, ck = idx & 3;          \
                uint4 v = make_uint4(0, 0, 0, 0);                               \
                if (row0 + r < M)                                               \
                    v = *(const uint4*)&Ab[(size_t)(row0 + r) * K + k0_ + ck * 8]; \
                pab[S][q] = v;                                                  \
            }                                                                   \
        } else {                                                                \
            _Pragma("unroll")                                                   \
            for (int q = 0; q < CA_F; ++q) {                                    \
                int idx = q * 256 + t; int r = idx >> 3, cf = idx & 7;          \
                float4 v = make_float4(0.f, 0.f, 0.f, 0.f);                     \
                if (row0 + r < M)                                               \
                    v = *(const float4*)&Af[(size_t)(row0 + r) * K + k0_ + cf * 4]; \
                paf[S][q] = v;                                                  \
            }                                                                   \
        }                                                                       \
        _Pragma("unroll")                                                       \
        for (int q = 0; q < CB; ++q) {                                          \
            int idx = q * 256 + t; int c = idx >> 2, ck = idx & 3;              \
            pb[S][q] = *(const uint4*)&Wt[(size_t)c * K + k0_ + ck * 8];        \
        }                                                                       \
    }

#define WRITE_TILE(S)                                                           \
    {   if constexpr (A_BF16) {                                                 \
            _Pragma("unroll")                                                   \
            for (int q = 0; q < CA_B; ++q) {                                    \
                int idx = q * 256 + t; int r = idx >> 2, ck = idx & 3;          \
                *(uint4*)&Al[r][ck * 8] = pab[S][q];                            \
            }                                                                   \
        } else {                                                                \
            _Pragma("unroll")                                                   \
            for (int q = 0; q < CA_F; ++q) {                                    \
                int idx = q * 256 + t; int r = idx >> 3, cf = idx & 7;          \
                float4 v = paf[S][q];                                           \
                uint2 pk;                                                       \
                pk.x = (unsigned)f2bf(v.x) | ((unsigned)f2bf(v.y) << 16);       \
                pk.y = (unsigned)f2bf(v.z) | ((unsigned)f2bf(v.w) << 16);       \
                *(uint2*)&Al[r][cf * 4] = pk;                                   \
            }                                                                   \
        }                                                                       \
        _Pragma("unroll")                                                       \
        for (int q = 0; q < CB; ++q) {                                          \
            int idx = q * 256 + t; int c = idx >> 2, ck = idx & 3;              \
            *(uint4*)&Bl[c][ck * 8] = pb[S][q];                                 \
        }                                                                       \
    }

#define COMPUTE()                                                               \
    {   short8 a_[4], b_[4];                                                    \
        _Pragma("unroll")                                                       \
        for (int i = 0; i < 4; ++i)                                             \
            a_[i] = *(const short8*)&Al[wm * 64 + i * 16 + fr][fk * 8];         \
        _Pragma("unroll")                                                       \
        for (int n = 0; n < 4; ++n)                                             \
            b_[n] = *(const short8*)&Bl[wn * 64 + n * 16 + fr][fk * 8];         \
        _Pragma("unroll")                                                       \
        for (int i = 0; i < 4; ++i)                                             \
            _Pragma("unroll")                                                   \
            for (int n = 0; n < 4; ++n)                                         \
                acc[i][n] = __builtin_amdgcn_mfma_f32_16x16x32_bf16(            \
                    a_[i], b_[n], acc[i][n], 0, 0, 0);                          \
    }

    LOAD_TILE(0, 0)
    for (int k0 = 0; k0 < K; k0 += 64) {
        WRITE_TILE(0)
        __syncthreads();
        if (k0 + 32 < K) LOAD_TILE(1, k0 + 32)
        COMPUTE()
        __syncthreads();
        if (k0 + 32 < K) {
            WRITE_TILE(1)
            __syncthreads();
            if (k0 + 64 < K) LOAD_TILE(0, k0 + 64)
            COMPUTE()
            __syncthreads();
        }
    }
#undef LOAD_TILE
#undef WRITE_TILE
#undef COMPUTE

    float*          Cf = (float*)Cv;
    unsigned short* Cb = (unsigned short*)Cv;
    #pragma unroll
    for (int i = 0; i < 4; ++i) {
        #pragma unroll
        for (int q = 0; q < 4; ++q) {
            int r = row0 + wm * 64 + i * 16 + fk * 4 + q;
            if (r >= M) continue;
            #pragma unroll
            for (int n = 0; n < 4; ++n) {
                int c = wn * 64 + n * 16 + fr;
                float v = acc[i][n][q];
                if constexpr (EPI == EPI_BIAS) v += bias[c];
                else if constexpr (EPI == EPI_LIN)
                    v = lrelu(v + bias[c]) + extra[(size_t)r * BN + c];
                else if constexpr (EPI == EPI_G)
                    v = lrelu(v + bias[c] + extra[(size_t)r * BN + c]);
                if constexpr (OUT_BF16) Cb[(size_t)r * BN + c] = f2bf(v);
                else                    Cf[(size_t)r * BN + c] = v;
            }
        }
    }
}

// ========== fused conv+lin for layers 2,3 (shared A[M,64], two 64->64 weights) ==========
// waves 0,1: C1[r] = A@W1 (bf16). waves 2,3: C2[r] = lrelu(A@W2+b2)+id (f32).
__global__ __launch_bounds__(256)
void gemm_dual64(const float* __restrict__ A, const unsigned short* __restrict__ Wt1,
                 const unsigned short* __restrict__ Wt2, const float* __restrict__ b2,
                 const float* __restrict__ id_emb,
                 unsigned short* __restrict__ C1, float* __restrict__ C2, int M)
{
    constexpr int K = 64;
    __shared__ __align__(16) unsigned short Al[128][32];
    __shared__ __align__(16) unsigned short B1l[64][32];
    __shared__ __align__(16) unsigned short B2l[64][32];

    const int t = threadIdx.x;
    const int wave = t >> 6, lane = t & 63;
    const int wsel = wave >> 1, wrow = wave & 1;
    const int row0 = blockIdx.x * 128;
    const int fr = lane & 15, fk = lane >> 4;

    float4 paf[2][4];
    uint4  pb1[2], pb2[2];
    f32x4  acc[4][4] = {};

#define LOAD_TILED(S, K0)                                                       \
    {   const int k0_ = (K0);                                                   \
        _Pragma("unroll")                                                       \
        for (int q = 0; q < 4; ++q) {                                           \
            int idx = q * 256 + t; int r = idx >> 3, cf = idx & 7;              \
            float4 v = make_float4(0.f, 0.f, 0.f, 0.f);                         \
            if (row0 + r < M)                                                   \
                v = *(const float4*)&A[(size_t)(row0 + r) * K + k0_ + cf * 4];  \
            paf[S][q] = v;                                                      \
        }                                                                       \
        {   int c = t >> 2, ck = t & 3;                                         \
            pb1[S] = *(const uint4*)&Wt1[(size_t)c * K + k0_ + ck * 8];         \
            pb2[S] = *(const uint4*)&Wt2[(size_t)c * K + k0_ + ck * 8];         \
        }                                                                       \
    }

#define WRITE_TILED(S)                                                          \
    {   _Pragma("unroll")                                                       \
        for (int q = 0; q < 4; ++q) {                                           \
            int idx = q * 256 + t; int r = idx >> 3, cf = idx & 7;              \
            float4 v = paf[S][q];                                               \
            uint2 pk;                                                           \
            pk.x = (unsigned)f2bf(v.x) | ((unsigned)f2bf(v.y) << 16);           \
            pk.y = (unsigned)f2bf(v.z) | ((unsigned)f2bf(v.w) << 16);           \
            *(uint2*)&Al[r][cf * 4] = pk;                                       \
        }                                                                       \
        {   int c = t >> 2, ck = t & 3;                                         \
            *(uint4*)&B1l[c][ck * 8] = pb1[S];                                  \
            *(uint4*)&B2l[c][ck * 8] = pb2[S];                                  \
        }                                                                       \
    }

#define COMPUTED()                                                              \
    {   const unsigned short (*Bs)[32] = wsel ? B2l : B1l;                      \
        short8 a_[4], b_[4];                                                    \
        _Pragma("unroll")                                                       \
        for (int i = 0; i < 4; ++i)                                             \
            a_[i] = *(const short8*)&Al[wrow * 64 + i * 16 + fr][fk * 8];       \
        _Pragma("unroll")                                                       \
        for (int n = 0; n < 4; ++n)                                             \
            b_[n] = *(const short8*)&Bs[n * 16 + fr][fk * 8];                   \
        _Pragma("unroll")                                                       \
        for (int i = 0; i < 4; ++i)                                             \
            _Pragma("unroll")                                                   \
            for (int n = 0; n < 4; ++n)                                         \
                acc[i][n] = __builtin_amdgcn_mfma_f32_16x16x32_bf16(            \
                    a_[i], b_[n], acc[i][n], 0, 0, 0);                          \
    }

    LOAD_TILED(0, 0)
    WRITE_TILED(0)
    __syncthreads();
    LOAD_TILED(1, 32)
    COMPUTED()
    __syncthreads();
    WRITE_TILED(1)
    __syncthreads();
    COMPUTED()
#undef LOAD_TILED
#undef WRITE_TILED
#undef COMPUTED

    #pragma unroll
    for (int i = 0; i < 4; ++i) {
        #pragma unroll
        for (int q = 0; q < 4; ++q) {
            int r = row0 + wrow * 64 + i * 16 + fk * 4 + q;
            if (r >= M) continue;
            #pragma unroll
            for (int n = 0; n < 4; ++n) {
                int c = n * 16 + fr;
                float v = acc[i][n][q];
                if (wsel == 0) {
                    C1[(size_t)r * 64 + c] = f2bf(v);
                } else {
                    C2[(size_t)r * 64 + c] =
                        lrelu(v + b2[c]) + id_emb[(size_t)r * 64 + c];
                }
            }
        }
    }
}

// ---------------- weight pre-convert (f32 [K][Nc] -> bf16 transposed [Nc][K]) ----------------

struct WtJob  { const float* w; unsigned short* wt; int K; int Nc; };
struct WtJobs { WtJob j[20]; };

__global__ __launch_bounds__(256)
void convert_wt(WtJobs jobs)
{
    WtJob jb = jobs.j[blockIdx.y];
    int n = jb.K * jb.Nc;
    int i = blockIdx.x * 256 + threadIdx.x;
    if (i >= n) return;
    int c = i / jb.K, k = i - c * jb.K;
    jb.wt[i] = f2bf(jb.w[(size_t)k * jb.Nc + c]);
}

// x[row] = (row < NU ? pref[row] : x[row]) / max(||.||2, 1e-12)
__global__ __launch_bounds__(256)
void build_norm_x(const float* __restrict__ pref, float* __restrict__ x, int nu, int n)
{
    int row  = blockIdx.x * 4 + (threadIdx.x >> 6);
    int lane = threadIdx.x & 63;
    if (row >= n) return;
    const float* srcp = (row < nu) ? (pref + (size_t)row * 256) : (x + (size_t)row * 256);
    float4 v = ((const float4*)srcp)[lane];
    float s = v.x * v.x + v.y * v.y + v.z * v.z + v.w * v.w;
    #pragma unroll
    for (int off = 32; off; off >>= 1) s += __shfl_xor(s, off);
    float scale = 1.f / fmaxf(sqrtf(s), 1e-12f);
    v.x *= scale; v.y *= scale; v.z *= scale; v.w *= scale;
    ((float4*)(x + (size_t)row * 256))[lane] = v;
}

// ---------------- CSR build ----------------

__global__ __launch_bounds__(256)
void zero_int(int* __restrict__ p, int n)
{
    int i = blockIdx.x * 256 + threadIdx.x;
    if (i < n) p[i] = 0;
}

__global__ __launch_bounds__(256)
void hist_dst(const int* __restrict__ dst, int* __restrict__ deg, int nE)
{
    int e = blockIdx.x * 256 + threadIdx.x;
    if (e < nE) atomicAdd(&deg[dst[e]], 1);
}

__global__ __launch_bounds__(256)
void scan_local(const int* __restrict__ deg, int* __restrict__ tmp,
                int* __restrict__ bsum, int n)
{
    __shared__ int s[256];
    int b = blockIdx.x, t = threadIdx.x;
    int base = b * 1024 + t * 4;
    int v[4];
    #pragma unroll
    for (int j = 0; j < 4; ++j) v[j] = (base + j < n) ? deg[base + j] : 0;
    int tsum = v[0] + v[1] + v[2] + v[3];
    s[t] = tsum;
    __syncthreads();
    for (int off = 1; off < 256; off <<= 1) {
        int x = (t >= off) ? s[t - off] : 0;
        __syncthreads();
        s[t] += x;
        __syncthreads();
    }
    int run = s[t] - tsum;
    #pragma unroll
    for (int j = 0; j < 4; ++j) {
        if (base + j < n) tmp[base + j] = run;
        run += v[j];
    }
    if (t == 255) bsum[b] = s[255];
}

__global__ void scan_bsum(int* __restrict__ bsum, int nb)
{
    if (threadIdx.x == 0 && blockIdx.x == 0) {
        int run = 0;
        for (int i = 0; i < nb; ++i) { int v = bsum[i]; bsum[i] = run; run += v; }
    }
}

__global__ __launch_bounds__(256)
void add_off(const int* __restrict__ tmp, const int* __restrict__ bsum,
             int* __restrict__ rowptr, int* __restrict__ cursor, int n, int total)
{
    int i = blockIdx.x * 256 + threadIdx.x;
    if (i < n) {
        int v = tmp[i] + bsum[i >> 10];
        rowptr[i] = v;
        cursor[i] = v;
    }
    if (i == 0) rowptr[n] = total;
}

__global__ __launch_bounds__(256)
void fill_col(const int* __restrict__ src, const int* __restrict__ dst,
              int* __restrict__ cursor, int* __restrict__ col, int nE)
{
    int e = blockIdx.x * 256 + threadIdx.x;
    if (e >= nE) return;
    int p = atomicAdd(&cursor[dst[e]], 1);
    col[p] = src[e];
}

// ---------------- gathers: h[row] = lrelu( sum m[col[i]] ), bf16 in/out ----------------

__global__ __launch_bounds__(256)
void gather256_bf16(const unsigned short* __restrict__ m, const int* __restrict__ rowptr,
                    const int* __restrict__ col, unsigned short* __restrict__ h, int n)
{
    int row  = blockIdx.x * 4 + (threadIdx.x >> 6);
    if (row >= n) return;
    int lane = threadIdx.x & 63;
    int s0 = rowptr[row], s1 = rowptr[row + 1];
    float a0 = 0.f, a1 = 0.f, a2 = 0.f, a3 = 0.f;
    for (int i = s0; i < s1; ++i) {
        int s = col[i];
        uint2 v = *(const uint2*)(m + (size_t)s * 256 + lane * 4);
        a0 += bf2f(v.x & 0xffffu); a1 += bf2f(v.x >> 16);
        a2 += bf2f(v.y & 0xffffu); a3 += bf2f(v.y >> 16);
    }
    uint2 o;
    o.x = (unsigned)f2bf(lrelu(a0)) | ((unsigned)f2bf(lrelu(a1)) << 16);
    o.y = (unsigned)f2bf(lrelu(a2)) | ((unsigned)f2bf(lrelu(a3)) << 16);
    *(uint2*)(h + (size_t)row * 256 + lane * 4) = o;
}

__global__ __launch_bounds__(256)
void gather64_bf16(const unsigned short* __restrict__ m, const int* __restrict__ rowptr,
                   const int* __restrict__ col, unsigned short* __restrict__ h, int n)
{
    int gid  = blockIdx.x * 256 + threadIdx.x;
    int row  = gid >> 5;
    if (row >= n) return;
    int c2 = gid & 31;
    int s0 = rowptr[row], s1 = rowptr[row + 1];
    float a0 = 0.f, a1 = 0.f;
    for (int i = s0; i < s1; ++i) {
        unsigned v = *(const unsigned*)(m + (size_t)col[i] * 64 + c2 * 2);
        a0 += bf2f(v & 0xffffu); a1 += bf2f(v >> 16);
    }
    unsigned o = (unsigned)f2bf(lrelu(a0)) | ((unsigned)f2bf(lrelu(a1)) << 16);
    *(unsigned*)(h + (size_t)row * 64 + c2 * 2) = o;
}

__global__ __launch_bounds__(256)
void combine_avg(const float* __restrict__ a, const float* __restrict__ b,
                 float* __restrict__ o, int n4)
{
    int i = blockIdx.x * 256 + threadIdx.x;
    if (i >= n4) return;
    float4 x = ((const float4*)a)[i], y = ((const float4*)b)[i];
    ((float4*)o)[i] = make_float4(0.5f * (x.x + y.x), 0.5f * (x.y + y.y),
                                  0.5f * (x.z + y.z), 0.5f * (x.w + y.w));
}

extern "C" void kernel_launch(void* const* d_in, const int* in_sizes, int n_in,
                              void* d_out, int out_size, void* d_ws, size_t ws_size,
                              hipStream_t stream)
{
    const float* v_feat = (const float*)d_in[0];
    const float* t_feat = (const float*)d_in[1];
    const float* id_emb = (const float*)d_in[2];
    const int*   edge   = (const int*)d_in[3];
    const int nE = in_sizes[3] / 2;
    const int* src = edge;
    const int* dst = edge + nE;

    float* ws = (float*)d_ws;
    float* X  = ws;                               // [N,256] f32
    float* XH = X  + (size_t)NC * 256;            // [N,64]  f32
    float* Xc = XH + (size_t)NC * 64;             // [N,64]  f32
    float* Vo = Xc + (size_t)NC * 64;             // [N,64]  f32
    unsigned short* Mb = (unsigned short*)(Vo + (size_t)NC * 64);  // [N,256] bf16
    unsigned short* Hb = Mb + (size_t)NC * 256;                    // [N,256] bf16
    unsigned short* Wt = Hb + (size_t)NC * 256;                    // bf16 weights
    int* iw = (int*)(Wt + 1001472);
    int* deg    = iw;
    int* tmp    = deg    + NC;
    int* rowptr = tmp    + NC;
    int* cursor = rowptr + NC + 1;
    int* bsum   = cursor + NC;
    int* col    = bsum   + 256;

    const int nchunks = (NC + 1023) / 1024;

    // per-modality weight order: mlp, conv1, conv2, conv3, lin1, lin2, lin3, g1, g2, g3
    const int kn[10][2] = {{0, 256}, {256, 256}, {64, 64}, {64, 64}, {256, 64},
                           {64, 64}, {64, 64}, {256, 64}, {64, 64}, {64, 64}};
    const int widx[10] = {1, 3, 4, 5, 6, 8, 10, 12, 14, 16};
    WtJobs jobs;
    unsigned short* WtP[2][10];
    unsigned short* wp = Wt;
    for (int p = 0; p < 2; ++p) {
        const int base = 4 + 18 * p;
        const int FD = in_sizes[p] / NIC;          // 2048 / 768
        for (int j = 0; j < 10; ++j) {
            int K = (j == 0) ? FD : kn[j][0];
            int Nc = kn[j][1];
            jobs.j[p * 10 + j] = WtJob{(const float*)d_in[base + widx[j]], wp, K, Nc};
            WtP[p][j] = wp;
            wp += (size_t)K * Nc;
            wp = (unsigned short*)(((size_t)wp + 15) & ~(size_t)15);
        }
    }
    convert_wt<<<dim3(2048, 20), 256, 0, stream>>>(jobs);

    zero_int<<<(NC + 255) / 256, 256, 0, stream>>>(deg, NC);
    hist_dst<<<(nE + 255) / 256, 256, 0, stream>>>(dst, deg, nE);
    scan_local<<<nchunks, 256, 0, stream>>>(deg, tmp, bsum, NC);
    scan_bsum<<<1, 64, 0, stream>>>(bsum, nchunks);
    add_off<<<(NC + 255) / 256, 256, 0, stream>>>(tmp, bsum, rowptr, cursor, NC, nE);
    fill_col<<<(nE + 255) / 256, 256, 0, stream>>>(src, dst, cursor, col, nE);

    const int g64_NI  = (NIC + 63) / 64;     // 938
    const int g64_N   = (NC + 63) / 64;      // 1563
    const int g256_N  = (NC + 255) / 256;    // 391
    const int g128_N  = (NC + 127) / 128;    // 782

    for (int p = 0; p < 2; ++p) {
        const int base = 4 + 18 * p;
        const float* feat  = p == 0 ? v_feat : t_feat;
        const int    FD    = in_sizes[p] / NIC;
        const float* pref  = (const float*)d_in[base + 0];
        const float* mlp_b = (const float*)d_in[base + 2];
        const float* lin_b[3] = {(const float*)d_in[base + 7],
                                 (const float*)d_in[base + 9],
                                 (const float*)d_in[base + 11]};
        const float* g_b[3]   = {(const float*)d_in[base + 13],
                                 (const float*)d_in[base + 15],
                                 (const float*)d_in[base + 17]};

        // x = l2norm(cat(pref, feat @ mlp_w + mlp_b))
        gemm_mfma<EPI_BIAS, false, false, 4><<<g64_NI, 256, 0, stream>>>(
            feat, WtP[p][0], mlp_b, nullptr, X + (size_t)NUC * 256, NIC, FD);
        build_norm_x<<<NC / 4, 256, 0, stream>>>(pref, X, NUC, NC);

        // ---- layer 1 (256 -> 64) ----
        gemm_mfma<EPI_NONE, false, true, 4><<<g64_N, 256, 0, stream>>>(
            X, WtP[p][1], nullptr, nullptr, Mb, NC, 256);
        gather256_bf16<<<(NC + 3) / 4, 256, 0, stream>>>(Mb, rowptr, col, Hb, NC);
        gemm_mfma<EPI_LIN, false, false, 1><<<g256_N, 256, 0, stream>>>(
            X, WtP[p][4], lin_b[0], id_emb, XH, NC, 256);
        gemm_mfma<EPI_G, true, false, 1><<<g256_N, 256, 0, stream>>>(
            Hb, WtP[p][7], g_b[0], XH, Xc, NC, 256);

        // ---- layers 2,3 (64 -> 64): fused conv+lin, then gather, then g ----
        for (int l = 1; l < 3; ++l) {
            gemm_dual64<<<g128_N, 256, 0, stream>>>(
                Xc, WtP[p][1 + l], WtP[p][4 + l], lin_b[l], id_emb, Mb, XH, NC);
            gather64_bf16<<<(NC * 32 + 255) / 256, 256, 0, stream>>>(Mb, rowptr, col, Hb, NC);
            float* dest = (l == 2 && p == 0) ? Vo : Xc;
            gemm_mfma<EPI_G, true, false, 1><<<g256_N, 256, 0, stream>>>(
                Hb, WtP[p][7 + l], g_b[l], XH, dest, NC, 64);
        }
    }

    combine_avg<<<(NC * 64 / 4 + 255) / 256, 256, 0, stream>>>(
        Vo, Xc, (float*)d_out, NC * 64 / 4);
}

// Round 5
// 1038.989 us; speedup vs baseline: 1.6245x; 1.6245x over previous
//
#include <hip/hip_runtime.h>
#include <cstddef>
#include <cstdint>

#define NUC 40000
#define NIC 60000
#define NC  100000

typedef short  short8 __attribute__((ext_vector_type(8)));
typedef float  f32x4  __attribute__((ext_vector_type(4)));

__device__ __forceinline__ float lrelu(float x) { return x >= 0.f ? x : 0.01f * x; }

__device__ __forceinline__ unsigned short f2bf(float f) {
    unsigned int u = __builtin_bit_cast(unsigned int, f);
    u += 0x7fffu + ((u >> 16) & 1u);           // RNE
    return (unsigned short)(u >> 16);
}
__device__ __forceinline__ float bf2f(unsigned int us) {
    return __builtin_bit_cast(float, us << 16);
}

// direct global->LDS DMA, 16B per lane; LDS dest = wave-uniform base + lane*16
__device__ __forceinline__ void gl_lds16(const unsigned short* g, unsigned short* l) {
    __builtin_amdgcn_global_load_lds(
        (const __attribute__((address_space(1))) unsigned int*)g,
        (__attribute__((address_space(3))) unsigned int*)l,
        16, 0, 0);
}

enum { EPI_NONE = 0, EPI_BIAS = 1, EPI_LIN = 2, EPI_G = 3 };

// ===== MFMA GEMM: double-buffered LDS, global_load_lds DMA for B (and bf16 A), =====
// ===== T14-split reg staging for f32 A, chunk-XOR swizzled LDS (both sides).    =====
// C[M,BN] = epi( A[M,K] @ Wt^T ), Wt bf16 [BN][K]. WN=4: 64x256 block; WN=1: 256x64.
template<int EPI, bool A_BF16, bool OUT_BF16, int WN>
__global__ __launch_bounds__(256, 2)
void gemm_mfma(const void* __restrict__ Av, const unsigned short* __restrict__ Wt,
               const float* __restrict__ bias, const float* __restrict__ extra,
               void* __restrict__ Cv, int M, int K)
{
    constexpr int BM  = (WN == 4) ? 64 : 256;
    constexpr int BN  = WN * 64;
    constexpr int IA  = BM / 64;          // A DMA issues per wave (bf16 A)
    constexpr int IB  = BN / 64;          // B DMA issues per wave
    constexpr int CHA = BM * 4 / 256;     // A 16B-chunks per thread (f32 A): 1 or 4

    __shared__ __align__(16) unsigned short Al[2][BM][32];
    __shared__ __align__(16) unsigned short Bl[2][BN][32];

    const int t = threadIdx.x;
    const int wave = t >> 6, lane = t & 63;
    const int wm = (WN == 4) ? 0 : wave;
    const int wn = (WN == 4) ? wave : 0;
    const int row0 = blockIdx.x * BM;
    const int fr = lane & 15, fk = lane >> 4;

    const float*          Af = (const float*)Av;
    const unsigned short* Ab = (const unsigned short*)Av;

    float4 pre[CHA][2];
    f32x4  acc[4][4] = {};

// issue DMA for B tile (+ A tile if bf16) of K-step K0 into buffer BUF.
// swizzle: LDS position chunk p holds content chunk p^(row&3); DMA writes LDS
// linearly, so the GLOBAL source address carries the inverse (= same) XOR.
#define STAGE_DMA(BUF, K0)                                                     \
    {   const int k0_ = (K0);                                                  \
        _Pragma("unroll")                                                      \
        for (int i = 0; i < IB; ++i) {                                         \
            int rb = (wave * IB + i) * 16;                                     \
            int r  = rb + (lane >> 2);                                         \
            int cs = (lane & 3) ^ (r & 3);                                     \
            gl_lds16(&Wt[(size_t)r * K + k0_ + cs * 8], &Bl[BUF][rb][0]);      \
        }                                                                      \
        if constexpr (A_BF16) {                                                \
            _Pragma("unroll")                                                  \
            for (int i = 0; i < IA; ++i) {                                     \
                int rb = (wave * IA + i) * 16;                                 \
                int r  = rb + (lane >> 2);                                     \
                int cs = (lane & 3) ^ (r & 3);                                 \
                if (row0 + r < M)                                              \
                    gl_lds16(&Ab[(size_t)(row0 + r) * K + k0_ + cs * 8],       \
                             &Al[BUF][rb][0]);                                 \
            }                                                                  \
        }                                                                      \
    }

// f32 A: issue global loads into registers (before COMPUTE)
#define AF_LOAD(K0)                                                            \
    {   const int k0_ = (K0);                                                  \
        _Pragma("unroll")                                                      \
        for (int q = 0; q < CHA; ++q) {                                        \
            int r = (t >> 2) + 64 * q;                                         \
            float4 v0 = make_float4(0.f, 0.f, 0.f, 0.f), v1 = v0;              \
            if (row0 + r < M) {                                                \
                const float* ap = &Af[(size_t)(row0 + r) * K + k0_ + (t & 3) * 8]; \
                v0 = *(const float4*)ap; v1 = *(const float4*)(ap + 4);        \
            }                                                                  \
            pre[q][0] = v0; pre[q][1] = v1;                                    \
        }                                                                      \
    }

// f32 A: convert + LDS write (after COMPUTE; compiler waits the loads)
#define AF_WRITE(BUF)                                                          \
    {   _Pragma("unroll")                                                      \
        for (int q = 0; q < CHA; ++q) {                                        \
            int r = (t >> 2) + 64 * q;                                         \
            int c = t & 3;                                                     \
            uint4 pk;                                                          \
            pk.x = (unsigned)f2bf(pre[q][0].x) | ((unsigned)f2bf(pre[q][0].y) << 16); \
            pk.y = (unsigned)f2bf(pre[q][0].z) | ((unsigned)f2bf(pre[q][0].w) << 16); \
            pk.z = (unsigned)f2bf(pre[q][1].x) | ((unsigned)f2bf(pre[q][1].y) << 16); \
            pk.w = (unsigned)f2bf(pre[q][1].z) | ((unsigned)f2bf(pre[q][1].w) << 16); \
            *(uint4*)&Al[BUF][r][(c ^ (r & 3)) * 8] = pk;                      \
        }                                                                      \
    }

#define COMPUTE(BUF)                                                           \
    {   short8 a_[4], b_[4];                                                   \
        const int ch = (fk ^ (fr & 3)) * 8;                                    \
        _Pragma("unroll")                                                      \
        for (int i = 0; i < 4; ++i)                                            \
            a_[i] = *(const short8*)&Al[BUF][wm * 64 + i * 16 + fr][ch];       \
        _Pragma("unroll")                                                      \
        for (int n = 0; n < 4; ++n)                                            \
            b_[n] = *(const short8*)&Bl[BUF][wn * 64 + n * 16 + fr][ch];       \
        _Pragma("unroll")                                                      \
        for (int i = 0; i < 4; ++i)                                            \
            _Pragma("unroll")                                                  \
            for (int n = 0; n < 4; ++n)                                        \
                acc[i][n] = __builtin_amdgcn_mfma_f32_16x16x32_bf16(           \
                    a_[i], b_[n], acc[i][n], 0, 0, 0);                         \
    }

    const int NT = K / 32;
    STAGE_DMA(0, 0)
    if constexpr (!A_BF16) { AF_LOAD(0) AF_WRITE(0) }
    __syncthreads();                       // drains prologue DMA (vmcnt 0)
    for (int tile = 0; tile < NT; ++tile) {
        const int cur = tile & 1, nxt = cur ^ 1;
        if (tile + 1 < NT) {
            STAGE_DMA(nxt, (tile + 1) * 32)          // DMA overlaps MFMA below
            if constexpr (!A_BF16) { AF_LOAD((tile + 1) * 32) }
        }
        COMPUTE(cur)
        if (tile + 1 < NT) {
            if constexpr (!A_BF16) { AF_WRITE(nxt) } // loads waited here, post-MFMA
        }
        __syncthreads();                   // drains this iteration's DMA
    }
#undef STAGE_DMA
#undef AF_LOAD
#undef AF_WRITE
#undef COMPUTE

    float*          Cf = (float*)Cv;
    unsigned short* Cb = (unsigned short*)Cv;
    #pragma unroll
    for (int i = 0; i < 4; ++i) {
        #pragma unroll
        for (int q = 0; q < 4; ++q) {
            int r = row0 + wm * 64 + i * 16 + fk * 4 + q;
            if (r >= M) continue;
            #pragma unroll
            for (int n = 0; n < 4; ++n) {
                int c = wn * 64 + n * 16 + fr;
                float v = acc[i][n][q];
                if constexpr (EPI == EPI_BIAS) v += bias[c];
                else if constexpr (EPI == EPI_LIN)
                    v = lrelu(v + bias[c]) + extra[(size_t)r * BN + c];
                else if constexpr (EPI == EPI_G)
                    v = lrelu(v + bias[c] + extra[(size_t)r * BN + c]);
                if constexpr (OUT_BF16) Cb[(size_t)r * BN + c] = f2bf(v);
                else                    Cf[(size_t)r * BN + c] = v;
            }
        }
    }
}

// ---------------- weight pre-convert (f32 [K][Nc] -> bf16 transposed [Nc][K]) ----------------

struct WtJob  { const float* w; unsigned short* wt; int K; int Nc; };
struct WtJobs { WtJob j[20]; };

__global__ __launch_bounds__(256)
void convert_wt(WtJobs jobs)
{
    WtJob jb = jobs.j[blockIdx.y];
    int n = jb.K * jb.Nc;
    int i = blockIdx.x * 256 + threadIdx.x;
    if (i >= n) return;
    int c = i / jb.K, k = i - c * jb.K;
    jb.wt[i] = f2bf(jb.w[(size_t)k * jb.Nc + c]);
}

// x[row] = (row < NU ? pref[row] : x[row]) / max(||.||2, 1e-12)
__global__ __launch_bounds__(256)
void build_norm_x(const float* __restrict__ pref, float* __restrict__ x, int nu, int n)
{
    int row  = blockIdx.x * 4 + (threadIdx.x >> 6);
    int lane = threadIdx.x & 63;
    if (row >= n) return;
    const float* srcp = (row < nu) ? (pref + (size_t)row * 256) : (x + (size_t)row * 256);
    float4 v = ((const float4*)srcp)[lane];
    float s = v.x * v.x + v.y * v.y + v.z * v.z + v.w * v.w;
    #pragma unroll
    for (int off = 32; off; off >>= 1) s += __shfl_xor(s, off);
    float scale = 1.f / fmaxf(sqrtf(s), 1e-12f);
    v.x *= scale; v.y *= scale; v.z *= scale; v.w *= scale;
    ((float4*)(x + (size_t)row * 256))[lane] = v;
}

// ---------------- CSR build ----------------

__global__ __launch_bounds__(256)
void zero_int(int* __restrict__ p, int n)
{
    int i = blockIdx.x * 256 + threadIdx.x;
    if (i < n) p[i] = 0;
}

__global__ __launch_bounds__(256)
void hist_dst(const int* __restrict__ dst, int* __restrict__ deg, int nE)
{
    int e = blockIdx.x * 256 + threadIdx.x;
    if (e < nE) atomicAdd(&deg[dst[e]], 1);
}

__global__ __launch_bounds__(256)
void scan_local(const int* __restrict__ deg, int* __restrict__ tmp,
                int* __restrict__ bsum, int n)
{
    __shared__ int s[256];
    int b = blockIdx.x, t = threadIdx.x;
    int base = b * 1024 + t * 4;
    int v[4];
    #pragma unroll
    for (int j = 0; j < 4; ++j) v[j] = (base + j < n) ? deg[base + j] : 0;
    int tsum = v[0] + v[1] + v[2] + v[3];
    s[t] = tsum;
    __syncthreads();
    for (int off = 1; off < 256; off <<= 1) {
        int x = (t >= off) ? s[t - off] : 0;
        __syncthreads();
        s[t] += x;
        __syncthreads();
    }
    int run = s[t] - tsum;
    #pragma unroll
    for (int j = 0; j < 4; ++j) {
        if (base + j < n) tmp[base + j] = run;
        run += v[j];
    }
    if (t == 255) bsum[b] = s[255];
}

__global__ void scan_bsum(int* __restrict__ bsum, int nb)
{
    if (threadIdx.x == 0 && blockIdx.x == 0) {
        int run = 0;
        for (int i = 0; i < nb; ++i) { int v = bsum[i]; bsum[i] = run; run += v; }
    }
}

__global__ __launch_bounds__(256)
void add_off(const int* __restrict__ tmp, const int* __restrict__ bsum,
             int* __restrict__ rowptr, int* __restrict__ cursor, int n, int total)
{
    int i = blockIdx.x * 256 + threadIdx.x;
    if (i < n) {
        int v = tmp[i] + bsum[i >> 10];
        rowptr[i] = v;
        cursor[i] = v;
    }
    if (i == 0) rowptr[n] = total;
}

__global__ __launch_bounds__(256)
void fill_col(const int* __restrict__ src, const int* __restrict__ dst,
              int* __restrict__ cursor, int* __restrict__ col, int nE)
{
    int e = blockIdx.x * 256 + threadIdx.x;
    if (e >= nE) return;
    int p = atomicAdd(&cursor[dst[e]], 1);
    col[p] = src[e];
}

// ---------------- gathers: h[row] = lrelu( sum m[col[i]] ), bf16 in/out ----------------

__global__ __launch_bounds__(256)
void gather256_bf16(const unsigned short* __restrict__ m, const int* __restrict__ rowptr,
                    const int* __restrict__ col, unsigned short* __restrict__ h, int n)
{
    int row  = blockIdx.x * 4 + (threadIdx.x >> 6);
    if (row >= n) return;
    int lane = threadIdx.x & 63;
    int s0 = rowptr[row], s1 = rowptr[row + 1];
    float a0 = 0.f, a1 = 0.f, a2 = 0.f, a3 = 0.f;
    for (int i = s0; i < s1; ++i) {
        int s = col[i];
        uint2 v = *(const uint2*)(m + (size_t)s * 256 + lane * 4);
        a0 += bf2f(v.x & 0xffffu); a1 += bf2f(v.x >> 16);
        a2 += bf2f(v.y & 0xffffu); a3 += bf2f(v.y >> 16);
    }
    uint2 o;
    o.x = (unsigned)f2bf(lrelu(a0)) | ((unsigned)f2bf(lrelu(a1)) << 16);
    o.y = (unsigned)f2bf(lrelu(a2)) | ((unsigned)f2bf(lrelu(a3)) << 16);
    *(uint2*)(h + (size_t)row * 256 + lane * 4) = o;
}

__global__ __launch_bounds__(256)
void gather64_bf16(const unsigned short* __restrict__ m, const int* __restrict__ rowptr,
                   const int* __restrict__ col, unsigned short* __restrict__ h, int n)
{
    int gid  = blockIdx.x * 256 + threadIdx.x;
    int row  = gid >> 5;
    if (row >= n) return;
    int c2 = gid & 31;
    int s0 = rowptr[row], s1 = rowptr[row + 1];
    float a0 = 0.f, a1 = 0.f;
    for (int i = s0; i < s1; ++i) {
        unsigned v = *(const unsigned*)(m + (size_t)col[i] * 64 + c2 * 2);
        a0 += bf2f(v & 0xffffu); a1 += bf2f(v >> 16);
    }
    unsigned o = (unsigned)f2bf(lrelu(a0)) | ((unsigned)f2bf(lrelu(a1)) << 16);
    *(unsigned*)(h + (size_t)row * 64 + c2 * 2) = o;
}

__global__ __launch_bounds__(256)
void combine_avg(const float* __restrict__ a, const float* __restrict__ b,
                 float* __restrict__ o, int n4)
{
    int i = blockIdx.x * 256 + threadIdx.x;
    if (i >= n4) return;
    float4 x = ((const float4*)a)[i], y = ((const float4*)b)[i];
    ((float4*)o)[i] = make_float4(0.5f * (x.x + y.x), 0.5f * (x.y + y.y),
                                  0.5f * (x.z + y.z), 0.5f * (x.w + y.w));
}

extern "C" void kernel_launch(void* const* d_in, const int* in_sizes, int n_in,
                              void* d_out, int out_size, void* d_ws, size_t ws_size,
                              hipStream_t stream)
{
    const float* v_feat = (const float*)d_in[0];
    const float* t_feat = (const float*)d_in[1];
    const float* id_emb = (const float*)d_in[2];
    const int*   edge   = (const int*)d_in[3];
    const int nE = in_sizes[3] / 2;
    const int* src = edge;
    const int* dst = edge + nE;

    float* ws = (float*)d_ws;
    float* X  = ws;                               // [N,256] f32
    float* XH = X  + (size_t)NC * 256;            // [N,64]  f32
    float* Xc = XH + (size_t)NC * 64;             // [N,64]  f32
    float* Vo = Xc + (size_t)NC * 64;             // [N,64]  f32
    unsigned short* Mb = (unsigned short*)(Vo + (size_t)NC * 64);  // [N,256] bf16
    unsigned short* Hb = Mb + (size_t)NC * 256;                    // [N,256] bf16
    unsigned short* Wt = Hb + (size_t)NC * 256;                    // bf16 weights
    int* iw = (int*)(Wt + 1001472);
    int* deg    = iw;
    int* tmp    = deg    + NC;
    int* rowptr = tmp    + NC;
    int* cursor = rowptr + NC + 1;
    int* bsum   = cursor + NC;
    int* col    = bsum   + 256;

    const int nchunks = (NC + 1023) / 1024;

    // per-modality weight order: mlp, conv1, conv2, conv3, lin1, lin2, lin3, g1, g2, g3
    const int kn[10][2] = {{0, 256}, {256, 256}, {64, 64}, {64, 64}, {256, 64},
                           {64, 64}, {64, 64}, {256, 64}, {64, 64}, {64, 64}};
    const int widx[10] = {1, 3, 4, 5, 6, 8, 10, 12, 14, 16};
    WtJobs jobs;
    unsigned short* WtP[2][10];
    unsigned short* wp = Wt;
    for (int p = 0; p < 2; ++p) {
        const int base = 4 + 18 * p;
        const int FD = in_sizes[p] / NIC;          // 2048 / 768
        for (int j = 0; j < 10; ++j) {
            int K = (j == 0) ? FD : kn[j][0];
            int Nc = kn[j][1];
            jobs.j[p * 10 + j] = WtJob{(const float*)d_in[base + widx[j]], wp, K, Nc};
            WtP[p][j] = wp;
            wp += (size_t)K * Nc;
            wp = (unsigned short*)(((size_t)wp + 15) & ~(size_t)15);
        }
    }
    convert_wt<<<dim3(2048, 20), 256, 0, stream>>>(jobs);

    zero_int<<<(NC + 255) / 256, 256, 0, stream>>>(deg, NC);
    hist_dst<<<(nE + 255) / 256, 256, 0, stream>>>(dst, deg, nE);
    scan_local<<<nchunks, 256, 0, stream>>>(deg, tmp, bsum, NC);
    scan_bsum<<<1, 64, 0, stream>>>(bsum, nchunks);
    add_off<<<(NC + 255) / 256, 256, 0, stream>>>(tmp, bsum, rowptr, cursor, NC, nE);
    fill_col<<<(nE + 255) / 256, 256, 0, stream>>>(src, dst, cursor, col, nE);

    const int g64_NI  = (NIC + 63) / 64;     // 938
    const int g64_N   = (NC + 63) / 64;      // 1563
    const int g256_N  = (NC + 255) / 256;    // 391

    for (int p = 0; p < 2; ++p) {
        const int base = 4 + 18 * p;
        const float* feat  = p == 0 ? v_feat : t_feat;
        const int    FD    = in_sizes[p] / NIC;
        const float* pref  = (const float*)d_in[base + 0];
        const float* mlp_b = (const float*)d_in[base + 2];
        const float* lin_b[3] = {(const float*)d_in[base + 7],
                                 (const float*)d_in[base + 9],
                                 (const float*)d_in[base + 11]};
        const float* g_b[3]   = {(const float*)d_in[base + 13],
                                 (const float*)d_in[base + 15],
                                 (const float*)d_in[base + 17]};

        // x = l2norm(cat(pref, feat @ mlp_w + mlp_b))
        gemm_mfma<EPI_BIAS, false, false, 4><<<g64_NI, 256, 0, stream>>>(
            feat, WtP[p][0], mlp_b, nullptr, X + (size_t)NUC * 256, NIC, FD);
        build_norm_x<<<NC / 4, 256, 0, stream>>>(pref, X, NUC, NC);

        // ---- layer 1 (256 -> 64) ----
        gemm_mfma<EPI_NONE, false, true, 4><<<g64_N, 256, 0, stream>>>(
            X, WtP[p][1], nullptr, nullptr, Mb, NC, 256);
        gather256_bf16<<<(NC + 3) / 4, 256, 0, stream>>>(Mb, rowptr, col, Hb, NC);
        gemm_mfma<EPI_LIN, false, false, 1><<<g256_N, 256, 0, stream>>>(
            X, WtP[p][4], lin_b[0], id_emb, XH, NC, 256);
        gemm_mfma<EPI_G, true, false, 1><<<g256_N, 256, 0, stream>>>(
            Hb, WtP[p][7], g_b[0], XH, Xc, NC, 256);

        // ---- layers 2,3 (64 -> 64) ----
        for (int l = 1; l < 3; ++l) {
            gemm_mfma<EPI_NONE, false, true, 1><<<g256_N, 256, 0, stream>>>(
                Xc, WtP[p][1 + l], nullptr, nullptr, Mb, NC, 64);
            gather64_bf16<<<(NC * 32 + 255) / 256, 256, 0, stream>>>(Mb, rowptr, col, Hb, NC);
            gemm_mfma<EPI_LIN, false, false, 1><<<g256_N, 256, 0, stream>>>(
                Xc, WtP[p][4 + l], lin_b[l], id_emb, XH, NC, 64);
            float* dest = (l == 2 && p == 0) ? Vo : Xc;
            gemm_mfma<EPI_G, true, false, 1><<<g256_N, 256, 0, stream>>>(
                Hb, WtP[p][7 + l], g_b[l], XH, dest, NC, 64);
        }
    }

    combine_avg<<<(NC * 64 / 4 + 255) / 256, 256, 0, stream>>>(
        Vo, Xc, (float*)d_out, NC * 64 / 4);
}

// Round 6
// 952.205 us; speedup vs baseline: 1.7725x; 1.0911x over previous
//
#include <hip/hip_runtime.h>
#include <cstddef>
#include <cstdint>

#define NUC 40000
#define NIC 60000
#define NC  100000

typedef short  short8 __attribute__((ext_vector_type(8)));
typedef float  f32x4  __attribute__((ext_vector_type(4)));
typedef unsigned short us;

__device__ __forceinline__ float lrelu(float x) { return x >= 0.f ? x : 0.01f * x; }

__device__ __forceinline__ us f2bf(float f) {
    unsigned int u = __builtin_bit_cast(unsigned int, f);
    u += 0x7fffu + ((u >> 16) & 1u);           // RNE
    return (us)(u >> 16);
}
__device__ __forceinline__ float bf2f(unsigned int v) {
    return __builtin_bit_cast(float, v << 16);
}
__device__ __forceinline__ unsigned pk2(float a, float b) {
    return (unsigned)f2bf(a) | ((unsigned)f2bf(b) << 16);
}

// direct global->LDS DMA, 16B/lane; LDS dest = wave-uniform base + lane*16
__device__ __forceinline__ void gl_lds16(const us* g, us* l) {
    __builtin_amdgcn_global_load_lds(
        (const __attribute__((address_space(1))) unsigned int*)g,
        (__attribute__((address_space(3))) unsigned int*)l,
        16, 0, 0);
}

enum { EPI_NONE = 0, EPI_BIAS = 1, EPI_LIN = 2, EPI_G = 3, EPI_NORM = 4 };

// ===== MFMA GEMM (R4 structure): dbuf LDS, DMA for B (and bf16 A), T14-split f32 A. =====
// EPI_NORM (WN=4 only): fused row-L2-normalize epilogue, bf16 out.
template<int EPI, bool A_BF16, bool OUT_BF16, int WN>
__global__ __launch_bounds__(256, 2)
void gemm_mfma(const void* __restrict__ Av, const us* __restrict__ Wt,
               const float* __restrict__ bias, const float* __restrict__ extra,
               void* __restrict__ Cv, int M, int K)
{
    constexpr int BM  = (WN == 4) ? 64 : 256;
    constexpr int BN  = WN * 64;
    constexpr int IA  = BM / 64;
    constexpr int IB  = BN / 64;
    constexpr int CHA = BM * 4 / 256;

    __shared__ __align__(16) us Al[2][BM][32];
    __shared__ __align__(16) us Bl[2][BN][32];
    __shared__ float snorm[4][64];

    const int t = threadIdx.x;
    const int wave = t >> 6, lane = t & 63;
    const int wm = (WN == 4) ? 0 : wave;
    const int wn = (WN == 4) ? wave : 0;
    const int row0 = blockIdx.x * BM;
    const int fr = lane & 15, fk = lane >> 4;

    const float* Af = (const float*)Av;
    const us*    Ab = (const us*)Av;

    float4 pre[CHA][2];
    f32x4  acc[4][4] = {};

#define STAGE_DMA(BUF, K0)                                                     \
    {   const int k0_ = (K0);                                                  \
        _Pragma("unroll")                                                      \
        for (int i = 0; i < IB; ++i) {                                         \
            int rb = (wave * IB + i) * 16;                                     \
            int r  = rb + (lane >> 2);                                         \
            int cs = (lane & 3) ^ (r & 3);                                     \
            gl_lds16(&Wt[(size_t)r * K + k0_ + cs * 8], &Bl[BUF][rb][0]);      \
        }                                                                      \
        if constexpr (A_BF16) {                                                \
            _Pragma("unroll")                                                  \
            for (int i = 0; i < IA; ++i) {                                     \
                int rb = (wave * IA + i) * 16;                                 \
                int r  = rb + (lane >> 2);                                     \
                int cs = (lane & 3) ^ (r & 3);                                 \
                if (row0 + r < M)                                              \
                    gl_lds16(&Ab[(size_t)(row0 + r) * K + k0_ + cs * 8],       \
                             &Al[BUF][rb][0]);                                 \
            }                                                                  \
        }                                                                      \
    }

#define AF_LOAD(K0)                                                            \
    {   const int k0_ = (K0);                                                  \
        _Pragma("unroll")                                                      \
        for (int q = 0; q < CHA; ++q) {                                        \
            int r = (t >> 2) + 64 * q;                                         \
            float4 v0 = make_float4(0.f, 0.f, 0.f, 0.f), v1 = v0;              \
            if (row0 + r < M) {                                                \
                const float* ap = &Af[(size_t)(row0 + r) * K + k0_ + (t & 3) * 8]; \
                v0 = *(const float4*)ap; v1 = *(const float4*)(ap + 4);        \
            }                                                                  \
            pre[q][0] = v0; pre[q][1] = v1;                                    \
        }                                                                      \
    }

#define AF_WRITE(BUF)                                                          \
    {   _Pragma("unroll")                                                      \
        for (int q = 0; q < CHA; ++q) {                                        \
            int r = (t >> 2) + 64 * q;                                         \
            int c = t & 3;                                                     \
            uint4 pk;                                                          \
            pk.x = pk2(pre[q][0].x, pre[q][0].y);                              \
            pk.y = pk2(pre[q][0].z, pre[q][0].w);                              \
            pk.z = pk2(pre[q][1].x, pre[q][1].y);                              \
            pk.w = pk2(pre[q][1].z, pre[q][1].w);                              \
            *(uint4*)&Al[BUF][r][(c ^ (r & 3)) * 8] = pk;                      \
        }                                                                      \
    }

#define COMPUTE(BUF)                                                           \
    {   short8 a_[4], b_[4];                                                   \
        const int ch = (fk ^ (fr & 3)) * 8;                                    \
        _Pragma("unroll")                                                      \
        for (int i = 0; i < 4; ++i)                                            \
            a_[i] = *(const short8*)&Al[BUF][wm * 64 + i * 16 + fr][ch];       \
        _Pragma("unroll")                                                      \
        for (int n = 0; n < 4; ++n)                                            \
            b_[n] = *(const short8*)&Bl[BUF][wn * 64 + n * 16 + fr][ch];       \
        _Pragma("unroll")                                                      \
        for (int i = 0; i < 4; ++i)                                            \
            _Pragma("unroll")                                                  \
            for (int n = 0; n < 4; ++n)                                        \
                acc[i][n] = __builtin_amdgcn_mfma_f32_16x16x32_bf16(           \
                    a_[i], b_[n], acc[i][n], 0, 0, 0);                         \
    }

    const int NT = K / 32;
    STAGE_DMA(0, 0)
    if constexpr (!A_BF16) { AF_LOAD(0) AF_WRITE(0) }
    __syncthreads();
    for (int tile = 0; tile < NT; ++tile) {
        const int cur = tile & 1, nxt = cur ^ 1;
        if (tile + 1 < NT) {
            STAGE_DMA(nxt, (tile + 1) * 32)
            if constexpr (!A_BF16) { AF_LOAD((tile + 1) * 32) }
        }
        COMPUTE(cur)
        if (tile + 1 < NT) {
            if constexpr (!A_BF16) { AF_WRITE(nxt) }
        }
        __syncthreads();
    }
#undef STAGE_DMA
#undef AF_LOAD
#undef AF_WRITE
#undef COMPUTE

    float* Cf = (float*)Cv;
    us*    Cb = (us*)Cv;

    if constexpr (EPI == EPI_NORM) {
        // fused row L2-norm over all 256 cols (WN=4: block covers the row)
        float bv[4];
        #pragma unroll
        for (int nn = 0; nn < 4; ++nn) bv[nn] = bias[wn * 64 + nn * 16 + fr];
        #pragma unroll
        for (int i = 0; i < 4; ++i) {
            #pragma unroll
            for (int q = 0; q < 4; ++q) {
                float p = 0.f;
                #pragma unroll
                for (int nn = 0; nn < 4; ++nn) {
                    float v = acc[i][nn][q] + bv[nn];
                    acc[i][nn][q] = v;
                    p += v * v;
                }
                p += __shfl_xor(p, 1); p += __shfl_xor(p, 2);
                p += __shfl_xor(p, 4); p += __shfl_xor(p, 8);
                if (fr == 0) snorm[wn][i * 16 + fk * 4 + q] = p;
            }
        }
        __syncthreads();
        #pragma unroll
        for (int i = 0; i < 4; ++i) {
            #pragma unroll
            for (int q = 0; q < 4; ++q) {
                int rl = i * 16 + fk * 4 + q;
                int r  = row0 + rl;
                if (r >= M) continue;
                float tot = snorm[0][rl] + snorm[1][rl] + snorm[2][rl] + snorm[3][rl];
                float scale = 1.f / fmaxf(sqrtf(tot), 1e-12f);
                #pragma unroll
                for (int nn = 0; nn < 4; ++nn)
                    Cb[(size_t)r * 256 + wn * 64 + nn * 16 + fr] =
                        f2bf(acc[i][nn][q] * scale);
            }
        }
        return;
    }

    #pragma unroll
    for (int i = 0; i < 4; ++i) {
        #pragma unroll
        for (int q = 0; q < 4; ++q) {
            int r = row0 + wm * 64 + i * 16 + fk * 4 + q;
            if (r >= M) continue;
            #pragma unroll
            for (int n = 0; n < 4; ++n) {
                int c = wn * 64 + n * 16 + fr;
                float v = acc[i][n][q];
                if constexpr (EPI == EPI_BIAS) v += bias[c];
                else if constexpr (EPI == EPI_LIN)
                    v = lrelu(v + bias[c]) + extra[(size_t)r * BN + c];
                else if constexpr (EPI == EPI_G)
                    v = lrelu(v + bias[c] + extra[(size_t)r * BN + c]);
                if constexpr (OUT_BF16) Cb[(size_t)r * BN + c] = f2bf(v);
                else                    Cf[(size_t)r * BN + c] = v;
            }
        }
    }
}

// ======== dual64: C1 = A@W1 (bf16), C2 = lrelu(A@W2+b2)+id (f32); A bf16 [M,64] ========
__global__ __launch_bounds__(512)
void dual64(const us* __restrict__ A, const us* __restrict__ W1t,
            const us* __restrict__ W2t, const float* __restrict__ b2,
            const float* __restrict__ id_emb,
            us* __restrict__ C1, float* __restrict__ C2, int M)
{
    __shared__ __align__(16) us Al[128][64];
    __shared__ __align__(16) us B1[64][64];
    __shared__ __align__(16) us B2[64][64];
    const int t = threadIdx.x, wave = t >> 6, lane = t & 63;
    const int row0 = blockIdx.x * 128;
    const int fr = lane & 15, fk = lane >> 4;

    #pragma unroll
    for (int i = 0; i < 2; ++i) {                 // A: 16 issues total
        int rb = (wave * 2 + i) * 8;
        int r  = rb + (lane >> 3);
        int cs = (lane & 7) ^ (r & 7);
        if (row0 + r < M)
            gl_lds16(&A[(size_t)(row0 + r) * 64 + cs * 8], &Al[rb][0]);
    }
    {                                              // B1,B2: 8 issues each
        int rb = wave * 8;
        int r  = rb + (lane >> 3);
        int cs = (lane & 7) ^ (r & 7);
        gl_lds16(&W1t[(size_t)r * 64 + cs * 8], &B1[rb][0]);
        gl_lds16(&W2t[(size_t)r * 64 + cs * 8], &B2[rb][0]);
    }
    __syncthreads();

    const int wsel = wave >> 2, wq = wave & 3;
    const us (*Bs)[64] = wsel ? B2 : B1;
    f32x4 acc[2][4] = {};
    #pragma unroll
    for (int kk = 0; kk < 2; ++kk) {
        const int ch = ((kk * 4 + fk) ^ (fr & 7)) * 8;
        short8 b_[4];
        #pragma unroll
        for (int nn = 0; nn < 4; ++nn)
            b_[nn] = *(const short8*)&Bs[nn * 16 + fr][ch];
        #pragma unroll
        for (int ii = 0; ii < 2; ++ii) {
            short8 a_ = *(const short8*)&Al[wq * 32 + ii * 16 + fr][ch];
            #pragma unroll
            for (int nn = 0; nn < 4; ++nn)
                acc[ii][nn] = __builtin_amdgcn_mfma_f32_16x16x32_bf16(
                    a_, b_[nn], acc[ii][nn], 0, 0, 0);
        }
    }
    #pragma unroll
    for (int ii = 0; ii < 2; ++ii) {
        #pragma unroll
        for (int q = 0; q < 4; ++q) {
            int r = row0 + wq * 32 + ii * 16 + fk * 4 + q;
            if (r >= M) continue;
            #pragma unroll
            for (int nn = 0; nn < 4; ++nn) {
                int c = nn * 16 + fr;
                float v = acc[ii][nn][q];
                if (wsel == 0) C1[(size_t)r * 64 + c] = f2bf(v);
                else C2[(size_t)r * 64 + c] =
                         lrelu(v + b2[c]) + id_emb[(size_t)r * 64 + c];
            }
        }
    }
}

// ======== fused gather + g-GEMM, K=256 (layer 1) ========
// Xout[r] = bf16( lrelu( lrelu(sum_{e in r} Mb[col[e]]) @ Gt^T + gb + XH[r] ) )
__global__ __launch_bounds__(512)
void gather_g256(const us* __restrict__ Mb, const int* __restrict__ rowptr,
                 const int* __restrict__ col, const us* __restrict__ Gt,
                 const float* __restrict__ gb, const float* __restrict__ XH,
                 us* __restrict__ Xout, int n)
{
    __shared__ __align__(16) us Hl[64][256];
    __shared__ __align__(16) us Bw[64][256];
    const int t = threadIdx.x, wave = t >> 6, lane = t & 63;
    const int row0 = blockIdx.x * 64;

    #pragma unroll
    for (int i = 0; i < 4; ++i) {                 // B: 32 issues (2 rows each)
        int rb = (wave * 4 + i) * 2;
        int r  = rb + (lane >> 5);
        int cs = (lane & 31) ^ (r & 7);
        gl_lds16(&Gt[(size_t)r * 256 + cs * 8], &Bw[rb][0]);
    }
    // gather: wave w -> rows w*8 .. w*8+8
    for (int rr = 0; rr < 8; ++rr) {
        int r  = wave * 8 + rr;
        int gr = row0 + r;
        float a0 = 0.f, a1 = 0.f, a2 = 0.f, a3 = 0.f;
        if (gr < n) {
            int i = rowptr[gr], s1 = rowptr[gr + 1];
            for (; i + 2 <= s1; i += 2) {
                int c0 = col[i], c1 = col[i + 1];
                uint2 v0 = *(const uint2*)(Mb + (size_t)c0 * 256 + lane * 4);
                uint2 v1 = *(const uint2*)(Mb + (size_t)c1 * 256 + lane * 4);
                a0 += bf2f(v0.x & 0xffffu) + bf2f(v1.x & 0xffffu);
                a1 += bf2f(v0.x >> 16)     + bf2f(v1.x >> 16);
                a2 += bf2f(v0.y & 0xffffu) + bf2f(v1.y & 0xffffu);
                a3 += bf2f(v0.y >> 16)     + bf2f(v1.y >> 16);
            }
            if (i < s1) {
                uint2 v0 = *(const uint2*)(Mb + (size_t)col[i] * 256 + lane * 4);
                a0 += bf2f(v0.x & 0xffffu); a1 += bf2f(v0.x >> 16);
                a2 += bf2f(v0.y & 0xffffu); a3 += bf2f(v0.y >> 16);
            }
        }
        uint2 o;
        o.x = pk2(lrelu(a0), lrelu(a1));
        o.y = pk2(lrelu(a2), lrelu(a3));
        *(uint2*)&Hl[r][((lane >> 1) ^ (r & 7)) * 8 + (lane & 1) * 4] = o;
    }
    __syncthreads();

    // compute: wave w -> row-tile rt=w>>1 (16 rows), col-half nh=w&1 (32 cols)
    const int fr = lane & 15, fk = lane >> 4;
    const int rt = wave >> 1, nh = wave & 1;
    f32x4 acc[2] = {};
    #pragma unroll
    for (int kk = 0; kk < 8; ++kk) {
        const int ch = ((kk * 4 + fk) ^ (fr & 7)) * 8;
        short8 a_ = *(const short8*)&Hl[rt * 16 + fr][ch];
        #pragma unroll
        for (int j = 0; j < 2; ++j) {
            short8 b_ = *(const short8*)&Bw[(nh * 2 + j) * 16 + fr][ch];
            acc[j] = __builtin_amdgcn_mfma_f32_16x16x32_bf16(a_, b_, acc[j], 0, 0, 0);
        }
    }
    #pragma unroll
    for (int q = 0; q < 4; ++q) {
        int r = row0 + rt * 16 + fk * 4 + q;
        if (r >= n) continue;
        #pragma unroll
        for (int j = 0; j < 2; ++j) {
            int c = (nh * 2 + j) * 16 + fr;
            Xout[(size_t)r * 64 + c] =
                f2bf(lrelu(acc[j][q] + gb[c] + XH[(size_t)r * 64 + c]));
        }
    }
}

// ======== fused gather + g-GEMM, K=64 (layers 2,3) ========
__global__ __launch_bounds__(512)
void gather_g64(const us* __restrict__ Mb, const int* __restrict__ rowptr,
                const int* __restrict__ col, const us* __restrict__ Gt,
                const float* __restrict__ gb, const float* __restrict__ XH,
                us* __restrict__ Xout, int n)
{
    __shared__ __align__(16) us Hl[128][64];
    __shared__ __align__(16) us Bw[64][64];
    const int t = threadIdx.x, wave = t >> 6, lane = t & 63;
    const int row0 = blockIdx.x * 128;

    {                                              // B: 8 issues (8 rows each)
        int rb = wave * 8;
        int r  = rb + (lane >> 3);
        int cs = (lane & 7) ^ (r & 7);
        gl_lds16(&Gt[(size_t)r * 64 + cs * 8], &Bw[rb][0]);
    }
    // gather: wave w -> rows w*16..+16, two rows per pass (half-waves)
    const int half = lane >> 5, hl = lane & 31;
    for (int rr = 0; rr < 8; ++rr) {
        int r  = wave * 16 + rr * 2 + half;
        int gr = row0 + r;
        float a0 = 0.f, a1 = 0.f;
        int i = 0, s1 = 0;
        if (gr < n) { i = rowptr[gr]; s1 = rowptr[gr + 1]; }
        for (; i + 2 <= s1; i += 2) {
            int c0 = col[i], c1 = col[i + 1];
            unsigned v0 = *(const unsigned*)(Mb + (size_t)c0 * 64 + hl * 2);
            unsigned v1 = *(const unsigned*)(Mb + (size_t)c1 * 64 + hl * 2);
            a0 += bf2f(v0 & 0xffffu) + bf2f(v1 & 0xffffu);
            a1 += bf2f(v0 >> 16)     + bf2f(v1 >> 16);
        }
        if (i < s1) {
            unsigned v0 = *(const unsigned*)(Mb + (size_t)col[i] * 64 + hl * 2);
            a0 += bf2f(v0 & 0xffffu); a1 += bf2f(v0 >> 16);
        }
        *(unsigned*)&Hl[r][((hl >> 2) ^ (r & 7)) * 8 + (hl & 3) * 2] =
            pk2(lrelu(a0), lrelu(a1));
    }
    __syncthreads();

    // compute: wave w -> rows w*16..+16, all 64 cols
    const int fr = lane & 15, fk = lane >> 4;
    f32x4 acc[4] = {};
    #pragma unroll
    for (int kk = 0; kk < 2; ++kk) {
        const int ch = ((kk * 4 + fk) ^ (fr & 7)) * 8;
        short8 a_ = *(const short8*)&Hl[wave * 16 + fr][ch];
        #pragma unroll
        for (int nn = 0; nn < 4; ++nn) {
            short8 b_ = *(const short8*)&Bw[nn * 16 + fr][ch];
            acc[nn] = __builtin_amdgcn_mfma_f32_16x16x32_bf16(a_, b_, acc[nn], 0, 0, 0);
        }
    }
    #pragma unroll
    for (int q = 0; q < 4; ++q) {
        int r = row0 + wave * 16 + fk * 4 + q;
        if (r >= n) continue;
        #pragma unroll
        for (int nn = 0; nn < 4; ++nn) {
            int c = nn * 16 + fr;
            Xout[(size_t)r * 64 + c] =
                f2bf(lrelu(acc[nn][q] + gb[c] + XH[(size_t)r * 64 + c]));
        }
    }
}

// ---------------- weight pre-convert (f32 [K][Nc] -> bf16 transposed [Nc][K]) ----------------

struct WtJob  { const float* w; us* wt; int K; int Nc; };
struct WtJobs { WtJob j[20]; };

__global__ __launch_bounds__(256)
void convert_wt(WtJobs jobs)
{
    WtJob jb = jobs.j[blockIdx.y];
    int n = jb.K * jb.Nc;
    int i = blockIdx.x * 256 + threadIdx.x;
    if (i >= n) return;
    int c = i / jb.K, k = i - c * jb.K;
    jb.wt[i] = f2bf(jb.w[(size_t)k * jb.Nc + c]);
}

// users: Xb[row] = bf16( pref[row] / max(||.||,1e-12) )
__global__ __launch_bounds__(256)
void norm_pref(const float* __restrict__ pref, us* __restrict__ xb, int nu)
{
    int row  = blockIdx.x * 4 + (threadIdx.x >> 6);
    int lane = threadIdx.x & 63;
    if (row >= nu) return;
    float4 v = ((const float4*)(pref + (size_t)row * 256))[lane];
    float s = v.x * v.x + v.y * v.y + v.z * v.z + v.w * v.w;
    #pragma unroll
    for (int off = 32; off; off >>= 1) s += __shfl_xor(s, off);
    float scale = 1.f / fmaxf(sqrtf(s), 1e-12f);
    uint2 o;
    o.x = pk2(v.x * scale, v.y * scale);
    o.y = pk2(v.z * scale, v.w * scale);
    ((uint2*)(xb + (size_t)row * 256))[lane] = o;
}

// ---------------- CSR build ----------------

__global__ __launch_bounds__(256)
void zero_int(int* __restrict__ p, int n)
{
    int i = blockIdx.x * 256 + threadIdx.x;
    if (i < n) p[i] = 0;
}

__global__ __launch_bounds__(256)
void hist_dst(const int* __restrict__ dst, int* __restrict__ deg, int nE)
{
    int e = blockIdx.x * 256 + threadIdx.x;
    if (e < nE) atomicAdd(&deg[dst[e]], 1);
}

__global__ __launch_bounds__(256)
void scan_local(const int* __restrict__ deg, int* __restrict__ tmp,
                int* __restrict__ bsum, int n)
{
    __shared__ int s[256];
    int b = blockIdx.x, t = threadIdx.x;
    int base = b * 1024 + t * 4;
    int v[4];
    #pragma unroll
    for (int j = 0; j < 4; ++j) v[j] = (base + j < n) ? deg[base + j] : 0;
    int tsum = v[0] + v[1] + v[2] + v[3];
    s[t] = tsum;
    __syncthreads();
    for (int off = 1; off < 256; off <<= 1) {
        int x = (t >= off) ? s[t - off] : 0;
        __syncthreads();
        s[t] += x;
        __syncthreads();
    }
    int run = s[t] - tsum;
    #pragma unroll
    for (int j = 0; j < 4; ++j) {
        if (base + j < n) tmp[base + j] = run;
        run += v[j];
    }
    if (t == 255) bsum[b] = s[255];
}

__global__ void scan_bsum(int* __restrict__ bsum, int nb)
{
    if (threadIdx.x == 0 && blockIdx.x == 0) {
        int run = 0;
        for (int i = 0; i < nb; ++i) { int v = bsum[i]; bsum[i] = run; run += v; }
    }
}

__global__ __launch_bounds__(256)
void add_off(const int* __restrict__ tmp, const int* __restrict__ bsum,
             int* __restrict__ rowptr, int* __restrict__ cursor, int n, int total)
{
    int i = blockIdx.x * 256 + threadIdx.x;
    if (i < n) {
        int v = tmp[i] + bsum[i >> 10];
        rowptr[i] = v;
        cursor[i] = v;
    }
    if (i == 0) rowptr[n] = total;
}

__global__ __launch_bounds__(256)
void fill_col(const int* __restrict__ src, const int* __restrict__ dst,
              int* __restrict__ cursor, int* __restrict__ col, int nE)
{
    int e = blockIdx.x * 256 + threadIdx.x;
    if (e >= nE) return;
    int p = atomicAdd(&cursor[dst[e]], 1);
    col[p] = src[e];
}

// out = (v + t) / 2, bf16 inputs -> f32 out
__global__ __launch_bounds__(256)
void combine_avg(const us* __restrict__ a, const us* __restrict__ b,
                 float* __restrict__ o, int n4)
{
    int i = blockIdx.x * 256 + threadIdx.x;
    if (i >= n4) return;
    uint2 x = ((const uint2*)a)[i], y = ((const uint2*)b)[i];
    float4 r;
    r.x = 0.5f * (bf2f(x.x & 0xffffu) + bf2f(y.x & 0xffffu));
    r.y = 0.5f * (bf2f(x.x >> 16)     + bf2f(y.x >> 16));
    r.z = 0.5f * (bf2f(x.y & 0xffffu) + bf2f(y.y & 0xffffu));
    r.w = 0.5f * (bf2f(x.y >> 16)     + bf2f(y.y >> 16));
    ((float4*)o)[i] = r;
}

extern "C" void kernel_launch(void* const* d_in, const int* in_sizes, int n_in,
                              void* d_out, int out_size, void* d_ws, size_t ws_size,
                              hipStream_t stream)
{
    const float* v_feat = (const float*)d_in[0];
    const float* t_feat = (const float*)d_in[1];
    const float* id_emb = (const float*)d_in[2];
    const int*   edge   = (const int*)d_in[3];
    const int nE = in_sizes[3] / 2;
    const int* srcp = edge;
    const int* dstp = edge + nE;

    // Workspace layout
    float* XH = (float*)d_ws;                       // [N,64]  f32
    us* Xb = (us*)(XH + (size_t)NC * 64);           // [N,256] bf16
    us* Xc = Xb + (size_t)NC * 256;                 // [N,64]  bf16
    us* Vo = Xc + (size_t)NC * 64;                  // [N,64]  bf16
    us* Mb = Vo + (size_t)NC * 64;                  // [N,256] bf16
    us* Wt = Mb + (size_t)NC * 256;                 // bf16 weights (~967K)
    int* iw = (int*)(Wt + 1001472);
    int* deg    = iw;
    int* tmp    = deg    + NC;
    int* rowptr = tmp    + NC;
    int* cursor = rowptr + NC + 1;
    int* bsum   = cursor + NC;
    int* col    = bsum   + 256;

    const int nchunks = (NC + 1023) / 1024;

    // per-modality weight order: mlp, conv1, conv2, conv3, lin1, lin2, lin3, g1, g2, g3
    const int kn[10][2] = {{0, 256}, {256, 256}, {64, 64}, {64, 64}, {256, 64},
                           {64, 64}, {64, 64}, {256, 64}, {64, 64}, {64, 64}};
    const int widx[10] = {1, 3, 4, 5, 6, 8, 10, 12, 14, 16};
    WtJobs jobs;
    us* WtP[2][10];
    us* wp = Wt;
    for (int p = 0; p < 2; ++p) {
        const int base = 4 + 18 * p;
        const int FD = in_sizes[p] / NIC;          // 2048 / 768
        for (int j = 0; j < 10; ++j) {
            int K = (j == 0) ? FD : kn[j][0];
            int Nc = kn[j][1];
            jobs.j[p * 10 + j] = WtJob{(const float*)d_in[base + widx[j]], wp, K, Nc};
            WtP[p][j] = wp;
            wp += (size_t)K * Nc;
            wp = (us*)(((size_t)wp + 15) & ~(size_t)15);
        }
    }
    convert_wt<<<dim3(2048, 20), 256, 0, stream>>>(jobs);

    zero_int<<<(NC + 255) / 256, 256, 0, stream>>>(deg, NC);
    hist_dst<<<(nE + 255) / 256, 256, 0, stream>>>(dstp, deg, nE);
    scan_local<<<nchunks, 256, 0, stream>>>(deg, tmp, bsum, NC);
    scan_bsum<<<1, 64, 0, stream>>>(bsum, nchunks);
    add_off<<<(NC + 255) / 256, 256, 0, stream>>>(tmp, bsum, rowptr, cursor, NC, nE);
    fill_col<<<(nE + 255) / 256, 256, 0, stream>>>(srcp, dstp, cursor, col, nE);

    const int g64_NI  = (NIC + 63) / 64;     // 938
    const int g64_N   = (NC + 63) / 64;      // 1563
    const int g256_N  = (NC + 255) / 256;    // 391
    const int g128_N  = (NC + 127) / 128;    // 782

    for (int p = 0; p < 2; ++p) {
        const int base = 4 + 18 * p;
        const float* feat  = p == 0 ? v_feat : t_feat;
        const int    FD    = in_sizes[p] / NIC;
        const float* pref  = (const float*)d_in[base + 0];
        const float* mlp_b = (const float*)d_in[base + 2];
        const float* lin_b[3] = {(const float*)d_in[base + 7],
                                 (const float*)d_in[base + 9],
                                 (const float*)d_in[base + 11]};
        const float* g_b[3]   = {(const float*)d_in[base + 13],
                                 (const float*)d_in[base + 15],
                                 (const float*)d_in[base + 17]};

        // Xb = l2norm(cat(pref, feat @ mlp_w + mlp_b)), bf16
        gemm_mfma<EPI_NORM, false, true, 4><<<g64_NI, 256, 0, stream>>>(
            feat, WtP[p][0], mlp_b, nullptr, Xb + (size_t)NUC * 256, NIC, FD);
        norm_pref<<<NUC / 4, 256, 0, stream>>>(pref, Xb, NUC);

        // ---- layer 1 (256 -> 64) ----
        gemm_mfma<EPI_NONE, true, true, 4><<<g64_N, 256, 0, stream>>>(
            Xb, WtP[p][1], nullptr, nullptr, Mb, NC, 256);
        gemm_mfma<EPI_LIN, true, false, 1><<<g256_N, 256, 0, stream>>>(
            Xb, WtP[p][4], lin_b[0], id_emb, XH, NC, 256);
        gather_g256<<<g64_N, 512, 0, stream>>>(
            Mb, rowptr, col, WtP[p][7], g_b[0], XH, Xc, NC);

        // ---- layers 2,3 (64 -> 64) ----
        for (int l = 1; l < 3; ++l) {
            dual64<<<g128_N, 512, 0, stream>>>(
                Xc, WtP[p][1 + l], WtP[p][4 + l], lin_b[l], id_emb, Mb, XH, NC);
            us* dest = (l == 2 && p == 0) ? Vo : Xc;
            gather_g64<<<g128_N, 512, 0, stream>>>(
                Mb, rowptr, col, WtP[p][7 + l], g_b[l], XH, dest, NC);
        }
    }

    combine_avg<<<(NC * 64 / 4 + 255) / 256, 256, 0, stream>>>(
        Vo, Xc, (float*)d_out, NC * 64 / 4);
}

// Round 7
// 848.601 us; speedup vs baseline: 1.9889x; 1.1221x over previous
//
#include <hip/hip_runtime.h>
#include <cstddef>
#include <cstdint>

#define NUC 40000
#define NIC 60000
#define NC  100000

typedef short  short8 __attribute__((ext_vector_type(8)));
typedef float  f32x4  __attribute__((ext_vector_type(4)));
typedef unsigned short us;

__device__ __forceinline__ float lrelu(float x) { return x >= 0.f ? x : 0.01f * x; }

__device__ __forceinline__ us f2bf(float f) {
    unsigned int u = __builtin_bit_cast(unsigned int, f);
    u += 0x7fffu + ((u >> 16) & 1u);           // RNE
    return (us)(u >> 16);
}
__device__ __forceinline__ float bf2f(unsigned int v) {
    return __builtin_bit_cast(float, v << 16);
}
__device__ __forceinline__ unsigned pk2(float a, float b) {
    return (unsigned)f2bf(a) | ((unsigned)f2bf(b) << 16);
}

// direct global->LDS DMA, 16B/lane; LDS dest = wave-uniform base + lane*16
__device__ __forceinline__ void gl_lds16(const us* g, us* l) {
    __builtin_amdgcn_global_load_lds(
        (const __attribute__((address_space(1))) unsigned int*)g,
        (__attribute__((address_space(3))) unsigned int*)l,
        16, 0, 0);
}

enum { EPI_NONE = 0, EPI_BIAS = 1, EPI_LIN = 2, EPI_G = 3, EPI_NORM = 4 };

struct GPair {
    const void* A[2]; const us* W[2];
    const float* bias[2]; const float* extra[2];
    void* C[2]; int K[2]; int M;
};

// ===== MFMA GEMM pair (R5-proven structure; blockIdx.y = modality) =====
template<int EPI, bool A_BF16, bool OUT_BF16, int WN>
__global__ __launch_bounds__(256, 3)
void gemm_pair(GPair P)
{
    constexpr int BM  = (WN == 4) ? 64 : 256;
    constexpr int BN  = WN * 64;
    constexpr int IA  = BM / 64;
    constexpr int IB  = BN / 64;
    constexpr int CHA = BM * 4 / 256;

    __shared__ __align__(16) us Al[2][BM][32];
    __shared__ __align__(16) us Bl[2][BN][32];
    __shared__ float snorm[4][64];

    const int p = blockIdx.y;
    const void* Av = P.A[p];
    const us*   Wt = P.W[p];
    const float* bias  = P.bias[p];
    const float* extra = P.extra[p];
    void* Cv = P.C[p];
    const int M = P.M, K = P.K[p];

    const int t = threadIdx.x;
    const int wave = t >> 6, lane = t & 63;
    const int wm = (WN == 4) ? 0 : wave;
    const int wn = (WN == 4) ? wave : 0;
    const int row0 = blockIdx.x * BM;
    const int fr = lane & 15, fk = lane >> 4;

    const float* Af = (const float*)Av;
    const us*    Ab = (const us*)Av;

    float4 pre[CHA][2];
    f32x4  acc[4][4] = {};

#define STAGE_DMA(BUF, K0)                                                     \
    {   const int k0_ = (K0);                                                  \
        _Pragma("unroll")                                                      \
        for (int i = 0; i < IB; ++i) {                                         \
            int rb = (wave * IB + i) * 16;                                     \
            int r  = rb + (lane >> 2);                                         \
            int cs = (lane & 3) ^ (r & 3);                                     \
            gl_lds16(&Wt[(size_t)r * K + k0_ + cs * 8], &Bl[BUF][rb][0]);      \
        }                                                                      \
        if constexpr (A_BF16) {                                                \
            _Pragma("unroll")                                                  \
            for (int i = 0; i < IA; ++i) {                                     \
                int rb = (wave * IA + i) * 16;                                 \
                int r  = rb + (lane >> 2);                                     \
                int cs = (lane & 3) ^ (r & 3);                                 \
                if (row0 + r < M)                                              \
                    gl_lds16(&Ab[(size_t)(row0 + r) * K + k0_ + cs * 8],       \
                             &Al[BUF][rb][0]);                                 \
            }                                                                  \
        }                                                                      \
    }

#define AF_LOAD(K0)                                                            \
    {   const int k0_ = (K0);                                                  \
        _Pragma("unroll")                                                      \
        for (int q = 0; q < CHA; ++q) {                                        \
            int r = (t >> 2) + 64 * q;                                         \
            float4 v0 = make_float4(0.f, 0.f, 0.f, 0.f), v1 = v0;              \
            if (row0 + r < M) {                                                \
                const float* ap = &Af[(size_t)(row0 + r) * K + k0_ + (t & 3) * 8]; \
                v0 = *(const float4*)ap; v1 = *(const float4*)(ap + 4);        \
            }                                                                  \
            pre[q][0] = v0; pre[q][1] = v1;                                    \
        }                                                                      \
    }

#define AF_WRITE(BUF)                                                          \
    {   _Pragma("unroll")                                                      \
        for (int q = 0; q < CHA; ++q) {                                        \
            int r = (t >> 2) + 64 * q;                                         \
            int c = t & 3;                                                     \
            uint4 pk;                                                          \
            pk.x = pk2(pre[q][0].x, pre[q][0].y);                              \
            pk.y = pk2(pre[q][0].z, pre[q][0].w);                              \
            pk.z = pk2(pre[q][1].x, pre[q][1].y);                              \
            pk.w = pk2(pre[q][1].z, pre[q][1].w);                              \
            *(uint4*)&Al[BUF][r][(c ^ (r & 3)) * 8] = pk;                      \
        }                                                                      \
    }

#define COMPUTE(BUF)                                                           \
    {   short8 a_[4], b_[4];                                                   \
        const int ch = (fk ^ (fr & 3)) * 8;                                    \
        _Pragma("unroll")                                                      \
        for (int i = 0; i < 4; ++i)                                            \
            a_[i] = *(const short8*)&Al[BUF][wm * 64 + i * 16 + fr][ch];       \
        _Pragma("unroll")                                                      \
        for (int n = 0; n < 4; ++n)                                            \
            b_[n] = *(const short8*)&Bl[BUF][wn * 64 + n * 16 + fr][ch];       \
        _Pragma("unroll")                                                      \
        for (int i = 0; i < 4; ++i)                                            \
            _Pragma("unroll")                                                  \
            for (int n = 0; n < 4; ++n)                                        \
                acc[i][n] = __builtin_amdgcn_mfma_f32_16x16x32_bf16(           \
                    a_[i], b_[n], acc[i][n], 0, 0, 0);                         \
    }

    const int NT = K / 32;
    STAGE_DMA(0, 0)
    if constexpr (!A_BF16) { AF_LOAD(0) AF_WRITE(0) }
    __syncthreads();
    for (int tile = 0; tile < NT; ++tile) {
        const int cur = tile & 1, nxt = cur ^ 1;
        if (tile + 1 < NT) {
            STAGE_DMA(nxt, (tile + 1) * 32)
            if constexpr (!A_BF16) { AF_LOAD((tile + 1) * 32) }
        }
        COMPUTE(cur)
        if (tile + 1 < NT) {
            if constexpr (!A_BF16) { AF_WRITE(nxt) }
        }
        __syncthreads();
    }
#undef STAGE_DMA
#undef AF_LOAD
#undef AF_WRITE
#undef COMPUTE

    float* Cf = (float*)Cv;
    us*    Cb = (us*)Cv;

    if constexpr (EPI == EPI_NORM) {
        float bv[4];
        #pragma unroll
        for (int nn = 0; nn < 4; ++nn) bv[nn] = bias[wn * 64 + nn * 16 + fr];
        #pragma unroll
        for (int i = 0; i < 4; ++i) {
            #pragma unroll
            for (int q = 0; q < 4; ++q) {
                float pp = 0.f;
                #pragma unroll
                for (int nn = 0; nn < 4; ++nn) {
                    float v = acc[i][nn][q] + bv[nn];
                    acc[i][nn][q] = v;
                    pp += v * v;
                }
                pp += __shfl_xor(pp, 1); pp += __shfl_xor(pp, 2);
                pp += __shfl_xor(pp, 4); pp += __shfl_xor(pp, 8);
                if (fr == 0) snorm[wn][i * 16 + fk * 4 + q] = pp;
            }
        }
        __syncthreads();
        #pragma unroll
        for (int i = 0; i < 4; ++i) {
            #pragma unroll
            for (int q = 0; q < 4; ++q) {
                int rl = i * 16 + fk * 4 + q;
                int r  = row0 + rl;
                if (r >= M) continue;
                float tot = snorm[0][rl] + snorm[1][rl] + snorm[2][rl] + snorm[3][rl];
                float scale = 1.f / fmaxf(sqrtf(tot), 1e-12f);
                #pragma unroll
                for (int nn = 0; nn < 4; ++nn)
                    Cb[(size_t)r * 256 + wn * 64 + nn * 16 + fr] =
                        f2bf(acc[i][nn][q] * scale);
            }
        }
        return;
    }

    #pragma unroll
    for (int i = 0; i < 4; ++i) {
        #pragma unroll
        for (int q = 0; q < 4; ++q) {
            int r = row0 + wm * 64 + i * 16 + fk * 4 + q;
            if (r >= M) continue;
            #pragma unroll
            for (int n = 0; n < 4; ++n) {
                int c = wn * 64 + n * 16 + fr;
                float v = acc[i][n][q];
                if constexpr (EPI == EPI_BIAS) v += bias[c];
                else if constexpr (EPI == EPI_LIN)
                    v = lrelu(v + bias[c]) + extra[(size_t)r * BN + c];
                else if constexpr (EPI == EPI_G)
                    v = lrelu(v + bias[c] + extra[(size_t)r * BN + c]);
                if constexpr (OUT_BF16) Cb[(size_t)r * BN + c] = f2bf(v);
                else                    Cf[(size_t)r * BN + c] = v;
            }
        }
    }
}

// ======== fused gather + g-GEMM pair, K=256 (layer 1) ========
struct GG256 {
    const us* Mb[2]; const us* Gt[2]; const float* gb[2];
    const float* XH[2]; us* Xout[2];
};
__global__ __launch_bounds__(512)
void gather_g256(GG256 P, const int* __restrict__ rowptr,
                 const int* __restrict__ col, int n)
{
    __shared__ __align__(16) us Hl[64][256];
    __shared__ __align__(16) us Bw[64][256];
    const int p = blockIdx.y;
    const us* Mb = P.Mb[p];
    const int t = threadIdx.x, wave = t >> 6, lane = t & 63;
    const int row0 = blockIdx.x * 64;

    #pragma unroll
    for (int i = 0; i < 4; ++i) {
        int rb = (wave * 4 + i) * 2;
        int r  = rb + (lane >> 5);
        int cs = (lane & 31) ^ (r & 7);
        gl_lds16(&P.Gt[p][(size_t)r * 256 + cs * 8], &Bw[rb][0]);
    }
    for (int rr = 0; rr < 8; ++rr) {
        int r  = wave * 8 + rr;
        int gr = row0 + r;
        float a0 = 0.f, a1 = 0.f, a2 = 0.f, a3 = 0.f;
        if (gr < n) {
            int i = rowptr[gr], s1 = rowptr[gr + 1];
            for (; i + 2 <= s1; i += 2) {
                int c0 = col[i], c1 = col[i + 1];
                uint2 v0 = *(const uint2*)(Mb + (size_t)c0 * 256 + lane * 4);
                uint2 v1 = *(const uint2*)(Mb + (size_t)c1 * 256 + lane * 4);
                a0 += bf2f(v0.x & 0xffffu) + bf2f(v1.x & 0xffffu);
                a1 += bf2f(v0.x >> 16)     + bf2f(v1.x >> 16);
                a2 += bf2f(v0.y & 0xffffu) + bf2f(v1.y & 0xffffu);
                a3 += bf2f(v0.y >> 16)     + bf2f(v1.y >> 16);
            }
            if (i < s1) {
                uint2 v0 = *(const uint2*)(Mb + (size_t)col[i] * 256 + lane * 4);
                a0 += bf2f(v0.x & 0xffffu); a1 += bf2f(v0.x >> 16);
                a2 += bf2f(v0.y & 0xffffu); a3 += bf2f(v0.y >> 16);
            }
        }
        uint2 o;
        o.x = pk2(lrelu(a0), lrelu(a1));
        o.y = pk2(lrelu(a2), lrelu(a3));
        *(uint2*)&Hl[r][((lane >> 1) ^ (r & 7)) * 8 + (lane & 1) * 4] = o;
    }
    __syncthreads();

    const int fr = lane & 15, fk = lane >> 4;
    const int rt = wave >> 1, nh = wave & 1;
    f32x4 acc[2] = {};
    #pragma unroll
    for (int kk = 0; kk < 8; ++kk) {
        const int ch = ((kk * 4 + fk) ^ (fr & 7)) * 8;
        short8 a_ = *(const short8*)&Hl[rt * 16 + fr][ch];
        #pragma unroll
        for (int j = 0; j < 2; ++j) {
            short8 b_ = *(const short8*)&Bw[(nh * 2 + j) * 16 + fr][ch];
            acc[j] = __builtin_amdgcn_mfma_f32_16x16x32_bf16(a_, b_, acc[j], 0, 0, 0);
        }
    }
    #pragma unroll
    for (int q = 0; q < 4; ++q) {
        int r = row0 + rt * 16 + fk * 4 + q;
        if (r >= n) continue;
        #pragma unroll
        for (int j = 0; j < 2; ++j) {
            int c = (nh * 2 + j) * 16 + fr;
            P.Xout[p][(size_t)r * 64 + c] =
                f2bf(lrelu(acc[j][q] + P.gb[p][c] + P.XH[p][(size_t)r * 64 + c]));
        }
    }
}

// ======== fused gather + lin + g, K=64 (layers 2,3) ========
// Xout[r] = lrelu( (lrelu ΣMb[col]) @ G + gb + lrelu(Xc[r]@L + lb) + id[r] )
struct GLG {
    const us* Mb[2]; const us* Gt[2]; const us* Lt[2];
    const float* gb[2]; const float* lb[2];
    const us* Xc[2]; us* Xout[2];
};
__global__ __launch_bounds__(512)
void gather_lin_g64(GLG P, const float* __restrict__ id_emb,
                    const int* __restrict__ rowptr, const int* __restrict__ col, int n)
{
    __shared__ __align__(16) us Hl[128][64];
    __shared__ __align__(16) us Xl[128][64];
    __shared__ __align__(16) us Bg[64][64];
    __shared__ __align__(16) us Blw[64][64];
    const int p = blockIdx.y;
    const us* Mb = P.Mb[p];
    const int t = threadIdx.x, wave = t >> 6, lane = t & 63;
    const int row0 = blockIdx.x * 128;

    #pragma unroll
    for (int i = 0; i < 2; ++i) {                  // Xc rows: 16 issues
        int rb = (wave * 2 + i) * 8;
        int r  = rb + (lane >> 3);
        int cs = (lane & 7) ^ (r & 7);
        if (row0 + r < n)
            gl_lds16(&P.Xc[p][(size_t)(row0 + r) * 64 + cs * 8], &Xl[rb][0]);
    }
    {                                              // weights: 8+8 issues
        int rb = wave * 8;
        int r  = rb + (lane >> 3);
        int cs = (lane & 7) ^ (r & 7);
        gl_lds16(&P.Gt[p][(size_t)r * 64 + cs * 8], &Bg[rb][0]);
        gl_lds16(&P.Lt[p][(size_t)r * 64 + cs * 8], &Blw[rb][0]);
    }
    const int half = lane >> 5, hl = lane & 31;
    for (int rr = 0; rr < 8; ++rr) {
        int r  = wave * 16 + rr * 2 + half;
        int gr = row0 + r;
        float a0 = 0.f, a1 = 0.f;
        int i = 0, s1 = 0;
        if (gr < n) { i = rowptr[gr]; s1 = rowptr[gr + 1]; }
        for (; i + 2 <= s1; i += 2) {
            int c0 = col[i], c1 = col[i + 1];
            unsigned v0 = *(const unsigned*)(Mb + (size_t)c0 * 64 + hl * 2);
            unsigned v1 = *(const unsigned*)(Mb + (size_t)c1 * 64 + hl * 2);
            a0 += bf2f(v0 & 0xffffu) + bf2f(v1 & 0xffffu);
            a1 += bf2f(v0 >> 16)     + bf2f(v1 >> 16);
        }
        if (i < s1) {
            unsigned v0 = *(const unsigned*)(Mb + (size_t)col[i] * 64 + hl * 2);
            a0 += bf2f(v0 & 0xffffu); a1 += bf2f(v0 >> 16);
        }
        *(unsigned*)&Hl[r][((hl >> 2) ^ (r & 7)) * 8 + (hl & 3) * 2] =
            pk2(lrelu(a0), lrelu(a1));
    }
    __syncthreads();

    const int fr = lane & 15, fk = lane >> 4;
    f32x4 aG[4] = {}, aL[4] = {};
    #pragma unroll
    for (int kk = 0; kk < 2; ++kk) {
        const int ch = ((kk * 4 + fk) ^ (fr & 7)) * 8;
        short8 ag = *(const short8*)&Hl[wave * 16 + fr][ch];
        short8 al = *(const short8*)&Xl[wave * 16 + fr][ch];
        #pragma unroll
        for (int nn = 0; nn < 4; ++nn) {
            short8 bg = *(const short8*)&Bg[nn * 16 + fr][ch];
            short8 bl = *(const short8*)&Blw[nn * 16 + fr][ch];
            aG[nn] = __builtin_amdgcn_mfma_f32_16x16x32_bf16(ag, bg, aG[nn], 0, 0, 0);
            aL[nn] = __builtin_amdgcn_mfma_f32_16x16x32_bf16(al, bl, aL[nn], 0, 0, 0);
        }
    }
    #pragma unroll
    for (int q = 0; q < 4; ++q) {
        int r = row0 + wave * 16 + fk * 4 + q;
        if (r >= n) continue;
        #pragma unroll
        for (int nn = 0; nn < 4; ++nn) {
            int c = nn * 16 + fr;
            float xhat = lrelu(aL[nn][q] + P.lb[p][c]) + id_emb[(size_t)r * 64 + c];
            P.Xout[p][(size_t)r * 64 + c] =
                f2bf(lrelu(aG[nn][q] + P.gb[p][c] + xhat));
        }
    }
}

// ---------------- weight pre-convert ----------------

struct WtJob  { const float* w; us* wt; int K; int Nc; };
struct WtJobs { WtJob j[20]; };

__global__ __launch_bounds__(256)
void convert_wt(WtJobs jobs)
{
    WtJob jb = jobs.j[blockIdx.y];
    int n = jb.K * jb.Nc;
    int i = blockIdx.x * 256 + threadIdx.x;
    if (i >= n) return;
    int c = i / jb.K, k = i - c * jb.K;
    jb.wt[i] = f2bf(jb.w[(size_t)k * jb.Nc + c]);
}

// users: Xb[row] = bf16( pref[row] / max(||.||,1e-12) ), pair
struct NP { const float* pref[2]; us* xb[2]; };
__global__ __launch_bounds__(256)
void norm_pref(NP P, int nu)
{
    int p    = blockIdx.y;
    int row  = blockIdx.x * 4 + (threadIdx.x >> 6);
    int lane = threadIdx.x & 63;
    if (row >= nu) return;
    float4 v = ((const float4*)(P.pref[p] + (size_t)row * 256))[lane];
    float s = v.x * v.x + v.y * v.y + v.z * v.z + v.w * v.w;
    #pragma unroll
    for (int off = 32; off; off >>= 1) s += __shfl_xor(s, off);
    float scale = 1.f / fmaxf(sqrtf(s), 1e-12f);
    uint2 o;
    o.x = pk2(v.x * scale, v.y * scale);
    o.y = pk2(v.z * scale, v.w * scale);
    ((uint2*)(P.xb[p] + (size_t)row * 256))[lane] = o;
}

// ---------------- CSR build ----------------

__global__ __launch_bounds__(256)
void hist_dst(const int* __restrict__ dst, int* __restrict__ deg, int nE)
{
    int e = blockIdx.x * 256 + threadIdx.x;
    if (e < nE) atomicAdd(&deg[dst[e]], 1);
}

__global__ __launch_bounds__(256)
void scan_local(const int* __restrict__ deg, int* __restrict__ tmp,
                int* __restrict__ bsum, int n)
{
    __shared__ int s[256];
    int b = blockIdx.x, t = threadIdx.x;
    int base = b * 1024 + t * 4;
    int v[4];
    #pragma unroll
    for (int j = 0; j < 4; ++j) v[j] = (base + j < n) ? deg[base + j] : 0;
    int tsum = v[0] + v[1] + v[2] + v[3];
    s[t] = tsum;
    __syncthreads();
    for (int off = 1; off < 256; off <<= 1) {
        int x = (t >= off) ? s[t - off] : 0;
        __syncthreads();
        s[t] += x;
        __syncthreads();
    }
    int run = s[t] - tsum;
    #pragma unroll
    for (int j = 0; j < 4; ++j) {
        if (base + j < n) tmp[base + j] = run;
        run += v[j];
    }
    if (t == 255) bsum[b] = s[255];
}

// rowptr/cursor = tmp + prefix(bsum); per-block serial prefix over <=98 chunks
__global__ __launch_bounds__(256)
void add_off2(const int* __restrict__ tmp, const int* __restrict__ bsum,
              int* __restrict__ rowptr, int* __restrict__ cursor, int n, int total)
{
    __shared__ int sp;
    if (threadIdx.x == 0) {
        int c = (blockIdx.x * 256) >> 10;
        int s = 0;
        for (int i = 0; i < c; ++i) s += bsum[i];
        sp = s;
    }
    __syncthreads();
    int i = blockIdx.x * 256 + threadIdx.x;
    if (i < n) {
        int v = tmp[i] + sp;
        rowptr[i] = v;
        cursor[i] = v;
    }
    if (i == 0) rowptr[n] = total;
}

__global__ __launch_bounds__(256)
void fill_col(const int* __restrict__ src, const int* __restrict__ dst,
              int* __restrict__ cursor, int* __restrict__ col, int nE)
{
    int e = blockIdx.x * 256 + threadIdx.x;
    if (e >= nE) return;
    int p = atomicAdd(&cursor[dst[e]], 1);
    col[p] = src[e];
}

// out = (v + t) / 2, bf16 inputs -> f32 out
__global__ __launch_bounds__(256)
void combine_avg(const us* __restrict__ a, const us* __restrict__ b,
                 float* __restrict__ o, int n4)
{
    int i = blockIdx.x * 256 + threadIdx.x;
    if (i >= n4) return;
    uint2 x = ((const uint2*)a)[i], y = ((const uint2*)b)[i];
    float4 r;
    r.x = 0.5f * (bf2f(x.x & 0xffffu) + bf2f(y.x & 0xffffu));
    r.y = 0.5f * (bf2f(x.x >> 16)     + bf2f(y.x >> 16));
    r.z = 0.5f * (bf2f(x.y & 0xffffu) + bf2f(y.y & 0xffffu));
    r.w = 0.5f * (bf2f(x.y >> 16)     + bf2f(y.y >> 16));
    ((float4*)o)[i] = r;
}

extern "C" void kernel_launch(void* const* d_in, const int* in_sizes, int n_in,
                              void* d_out, int out_size, void* d_ws, size_t ws_size,
                              hipStream_t stream)
{
    const float* id_emb = (const float*)d_in[2];
    const int*   edge   = (const int*)d_in[3];
    const int nE = in_sizes[3] / 2;
    const int* srcp = edge;
    const int* dstp = edge + nE;

    // Workspace layout
    float* XH_[2];
    XH_[0] = (float*)d_ws;
    XH_[1] = XH_[0] + (size_t)NC * 64;
    us* ub = (us*)(XH_[1] + (size_t)NC * 64);
    us* Xb_[2] = { ub, ub + (size_t)NC * 256 };
    us* Xc_[2] = { Xb_[1] + (size_t)NC * 256, Xb_[1] + (size_t)NC * 256 + (size_t)NC * 64 };
    us* Mb_[2] = { Xc_[1] + (size_t)NC * 64, Xc_[1] + (size_t)NC * 64 + (size_t)NC * 256 };
    us* Wt = Mb_[1] + (size_t)NC * 256;
    int* iw = (int*)(Wt + 1001472);
    int* deg    = iw;
    int* tmp    = deg    + NC;
    int* rowptr = tmp    + NC;
    int* cursor = rowptr + NC + 1;
    int* bsum   = cursor + NC;
    int* col    = bsum   + 256;

    const int nchunks = (NC + 1023) / 1024;

    // per-modality weight order: mlp, conv1, conv2, conv3, lin1, lin2, lin3, g1, g2, g3
    const int kn[10][2] = {{0, 256}, {256, 256}, {64, 64}, {64, 64}, {256, 64},
                           {64, 64}, {64, 64}, {256, 64}, {64, 64}, {64, 64}};
    const int widx[10] = {1, 3, 4, 5, 6, 8, 10, 12, 14, 16};
    WtJobs jobs;
    us* WtP[2][10];
    us* wp = Wt;
    int FD[2];
    for (int p = 0; p < 2; ++p) {
        const int base = 4 + 18 * p;
        FD[p] = in_sizes[p] / NIC;                 // 2048 / 768
        for (int j = 0; j < 10; ++j) {
            int K = (j == 0) ? FD[p] : kn[j][0];
            int Nc = kn[j][1];
            jobs.j[p * 10 + j] = WtJob{(const float*)d_in[base + widx[j]], wp, K, Nc};
            WtP[p][j] = wp;
            wp += (size_t)K * Nc;
            wp = (us*)(((size_t)wp + 15) & ~(size_t)15);
        }
    }
    convert_wt<<<dim3(2048, 20), 256, 0, stream>>>(jobs);

    // CSR
    hipMemsetAsync(deg, 0, NC * sizeof(int), stream);
    hist_dst<<<(nE + 255) / 256, 256, 0, stream>>>(dstp, deg, nE);
    scan_local<<<nchunks, 256, 0, stream>>>(deg, tmp, bsum, NC);
    add_off2<<<(NC + 255) / 256, 256, 0, stream>>>(tmp, bsum, rowptr, cursor, NC, nE);
    fill_col<<<(nE + 255) / 256, 256, 0, stream>>>(srcp, dstp, cursor, col, nE);

    const float* bias_of[2][7];   // [p]: mlp_b, lin_b1..3, g_b1..3
    for (int p = 0; p < 2; ++p) {
        const int base = 4 + 18 * p;
        bias_of[p][0] = (const float*)d_in[base + 2];
        bias_of[p][1] = (const float*)d_in[base + 7];
        bias_of[p][2] = (const float*)d_in[base + 9];
        bias_of[p][3] = (const float*)d_in[base + 11];
        bias_of[p][4] = (const float*)d_in[base + 13];
        bias_of[p][5] = (const float*)d_in[base + 15];
        bias_of[p][6] = (const float*)d_in[base + 17];
    }

    const int g64_NI = (NIC + 63) / 64;      // 938
    const int g64_N  = (NC + 63) / 64;       // 1563
    const int g256_N = (NC + 255) / 256;     // 391
    const int g128_N = (NC + 127) / 128;     // 782

    // ---- both-modality MLP with fused L2-norm ----
    {
        GPair Pm = {};
        Pm.M = NIC;
        Pm.A[0] = d_in[0];        Pm.A[1] = d_in[1];
        Pm.W[0] = WtP[0][0];      Pm.W[1] = WtP[1][0];
        Pm.bias[0] = bias_of[0][0]; Pm.bias[1] = bias_of[1][0];
        Pm.C[0] = Xb_[0] + (size_t)NUC * 256;
        Pm.C[1] = Xb_[1] + (size_t)NUC * 256;
        Pm.K[0] = FD[0]; Pm.K[1] = FD[1];
        gemm_pair<EPI_NORM, false, true, 4><<<dim3(g64_NI, 2), 256, 0, stream>>>(Pm);
    }
    {
        NP Pn = {};
        Pn.pref[0] = (const float*)d_in[4];
        Pn.pref[1] = (const float*)d_in[22];
        Pn.xb[0] = Xb_[0]; Pn.xb[1] = Xb_[1];
        norm_pref<<<dim3(NUC / 4, 2), 256, 0, stream>>>(Pn, NUC);
    }

    // ---- layer 1 (256 -> 64) ----
    {
        GPair Pc = {};
        Pc.M = NC; Pc.K[0] = Pc.K[1] = 256;
        Pc.A[0] = Xb_[0]; Pc.A[1] = Xb_[1];
        Pc.W[0] = WtP[0][1]; Pc.W[1] = WtP[1][1];
        Pc.C[0] = Mb_[0]; Pc.C[1] = Mb_[1];
        gemm_pair<EPI_NONE, true, true, 4><<<dim3(g64_N, 2), 256, 0, stream>>>(Pc);
    }
    {
        GPair Pl = {};
        Pl.M = NC; Pl.K[0] = Pl.K[1] = 256;
        Pl.A[0] = Xb_[0]; Pl.A[1] = Xb_[1];
        Pl.W[0] = WtP[0][4]; Pl.W[1] = WtP[1][4];
        Pl.bias[0] = bias_of[0][1]; Pl.bias[1] = bias_of[1][1];
        Pl.extra[0] = id_emb; Pl.extra[1] = id_emb;
        Pl.C[0] = XH_[0]; Pl.C[1] = XH_[1];
        gemm_pair<EPI_LIN, true, false, 1><<<dim3(g256_N, 2), 256, 0, stream>>>(Pl);
    }
    {
        GG256 Pg = {};
        for (int p = 0; p < 2; ++p) {
            Pg.Mb[p] = Mb_[p]; Pg.Gt[p] = WtP[p][7]; Pg.gb[p] = bias_of[p][4];
            Pg.XH[p] = XH_[p]; Pg.Xout[p] = Xc_[p];
        }
        gather_g256<<<dim3(g64_N, 2), 512, 0, stream>>>(Pg, rowptr, col, NC);
    }

    // ---- layers 2,3 (64 -> 64): conv pair, then fused gather+lin+g ----
    for (int l = 1; l < 3; ++l) {
        GPair Pc = {};
        Pc.M = NC; Pc.K[0] = Pc.K[1] = 64;
        Pc.A[0] = Xc_[0]; Pc.A[1] = Xc_[1];
        Pc.W[0] = WtP[0][1 + l]; Pc.W[1] = WtP[1][1 + l];
        Pc.C[0] = Mb_[0]; Pc.C[1] = Mb_[1];
        gemm_pair<EPI_NONE, true, true, 1><<<dim3(g256_N, 2), 256, 0, stream>>>(Pc);

        GLG Pg = {};
        for (int p = 0; p < 2; ++p) {
            Pg.Mb[p] = Mb_[p];
            Pg.Gt[p] = WtP[p][7 + l];
            Pg.Lt[p] = WtP[p][4 + l];
            Pg.gb[p] = bias_of[p][4 + l];
            Pg.lb[p] = bias_of[p][1 + l];
            Pg.Xc[p] = Xc_[p];
            Pg.Xout[p] = Xc_[p];     // in-place: each row read only by its own block
        }
        gather_lin_g64<<<dim3(g128_N, 2), 512, 0, stream>>>(Pg, id_emb, rowptr, col, NC);
    }

    combine_avg<<<(NC * 64 / 4 + 255) / 256, 256, 0, stream>>>(
        Xc_[0], Xc_[1], (float*)d_out, NC * 64 / 4);
}